// Round 4
// baseline (17258.955 us; speedup 1.0000x reference)
//
#include <hip/hip_runtime.h>

#define TDEC 400
#define NTH 512
#define NWG 512

typedef float f32x4 __attribute__((ext_vector_type(4)));
typedef unsigned u32x4 __attribute__((ext_vector_type(4)));
typedef unsigned u32x2 __attribute__((ext_vector_type(2)));

// ---------------- ws layout (float offsets) ----------------
#define OFF_BAR   0
#define OFF_ATTH  11264
#define OFF_H1    44032
#define OFF_H2    76800
#define OFF_CURP  109568       /* ctx buffer parity 0 [64][256] */
#define OFF_ATTS  125952       /* attS [2][64] */
#define OFF_Q     126208       /* ctx buffer parity 1 [64][256] */
#define ZERO_FLOATS 142592     /* memset covers BAR..Q inclusive */
#define OFF_D1    142592
#define OFF_SUMS  158976
#define OFF_C1    184576
#define OFF_PRE   185600       /* bf16 [400][64][128] */
#define OFF_PMB   1824000      /* bf16 [64][512][256] */
#define OFF_ENCB  6018304      /* bf16 [64][512][256] */
#define OFF_D2A   10212608     /* fp32 [400][256][64]; setup overlays below */
#define T_WIT_A   10212608
#define T_WHT_A   10507520
#define T_M1T     10704128
#define T_WHT1    11097344
#define T_PJT     11293952
#define T_WIT2    11425024
#define T_WHT2    11621632
#define T_QWT     11818240
#define T_M1      11883776
#define OFF_BLOB  16766208     /* bf16: 64 slices x BLOB_STR */
// total 17,618,176 floats = 70.5 MB

#define BLOB_N   26112
#define BLOB_STR 26624
// blob section offsets (ushort units)
#define BO_AI  0
#define BO_AH  4608
#define BO_Q   7680
#define BO_M1  8704
#define BO_H1  14848
#define BO_PJ  17920
#define BO_I2  19968
#define BO_H2  23040

#define AOFF 4096000
#define GOFF 17203200          /* gates region; doubles as QT scratch during decoder */

// group-local barrier counter slots (int offsets); group g adds +g*64
#define MSTI  (8*1024)
#define GENI  (9*1024)
#define FAILI (10*1024)

__device__ __forceinline__ float fsig(float x){ return 1.0f/(1.0f+__expf(-x)); }
__device__ __forceinline__ float ftanh(float x){ float e = __expf(2.0f*x); return 1.0f - 2.0f/(e+1.0f); }
__device__ __forceinline__ float blo(unsigned u){ return __uint_as_float(u<<16); }
__device__ __forceinline__ float bhi(unsigned u){ return __uint_as_float(u & 0xffff0000u); }

__device__ __forceinline__ f32x4 cload16(const float* p){
  f32x4 r;
  asm volatile("global_load_dwordx4 %0, %1, off sc0 sc1" : "=v"(r) : "v"(p));
  return r;
}
__device__ __forceinline__ f32x4 cload16w(const float* p){
  f32x4 r;
  asm volatile("global_load_dwordx4 %0, %1, off sc0 sc1\n\ts_waitcnt vmcnt(0)" : "=v"(r) : "v"(p));
  return r;
}
__device__ __forceinline__ u32x4 cload16u(const unsigned short* p){
  u32x4 r;
  asm volatile("global_load_dwordx4 %0, %1, off sc0 sc1" : "=v"(r) : "v"(p));
  return r;
}
__device__ __forceinline__ float aload4(const float* p){
  unsigned u = __hip_atomic_load((const unsigned*)p, __ATOMIC_RELAXED, __HIP_MEMORY_SCOPE_AGENT);
  return __uint_as_float(u);
}
__device__ __forceinline__ void astore4(float* p, float v){
  __hip_atomic_store((unsigned*)p, __float_as_uint(v), __ATOMIC_RELAXED, __HIP_MEMORY_SCOPE_AGENT);
}
__device__ __forceinline__ void aadd(float* p, float v){
  __hip_atomic_fetch_add(p, v, __ATOMIC_RELAXED, __HIP_MEMORY_SCOPE_AGENT);
}
__device__ __forceinline__ int aloadi(const int* p){
  return __hip_atomic_load(p, __ATOMIC_RELAXED, __HIP_MEMORY_SCOPE_AGENT);
}

// LDS-only barrier: does NOT drain vmcnt (global stores/prefetches stay in
// flight; gbar's vmcnt(0) provides cross-WG visibility).
__device__ __forceinline__ void ldsbar(){
  __builtin_amdgcn_sched_barrier(0);
  asm volatile("s_waitcnt lgkmcnt(0)" ::: "memory");
  __builtin_amdgcn_s_barrier();
  __builtin_amdgcn_sched_barrier(0);
}

// group-local (64-WG) fence-free barrier: monotonic counters, relaxed agent
// atomics. 8 arrival counters x 8 arrivals per round, per group (g=0..7).
__device__ __forceinline__ void gbar(int* bar, int g, int l, int n){
  asm volatile("s_waitcnt vmcnt(0)" ::: "memory");
  __syncthreads();
  if (threadIdx.x == 0){
    if (aloadi(&bar[FAILI]) == 0){
      int a = __hip_atomic_fetch_add(&bar[(l&7)*1024 + g*64], 1, __ATOMIC_RELAXED, __HIP_MEMORY_SCOPE_AGENT);
      if (a == 8*n - 1){
        int m = __hip_atomic_fetch_add(&bar[MSTI + g*64], 1, __ATOMIC_RELAXED, __HIP_MEMORY_SCOPE_AGENT);
        if (m == 8*n - 1)
          __hip_atomic_store(&bar[GENI + g*64], n, __ATOMIC_RELAXED, __HIP_MEMORY_SCOPE_AGENT);
      }
      int sp = 0;
      while (aloadi(&bar[GENI + g*64]) < n){
        __builtin_amdgcn_s_sleep(1);
        if (++sp > (1<<20)){
          __hip_atomic_store(&bar[FAILI], 1, __ATOMIC_RELAXED, __HIP_MEMORY_SCOPE_AGENT);
          break;
        }
      }
    }
  }
  __syncthreads();
}

__device__ __forceinline__ unsigned short f2bf(float f){
  unsigned u = __float_as_uint(f);
  return (unsigned short)((u + 0x7fffu + ((u>>16)&1u)) >> 16);
}

// bf16-weight dot with dual f32x4 accumulators (8x ILP vs scalar acc chain)
template<int N8>
__device__ __forceinline__ float bdot(const unsigned short* wr, const float* xr){
  f32x4 accA = 0.f, accB = 0.f;
  #pragma unroll 4
  for (int k = 0; k < N8; ++k){
    u32x4 u = *(const u32x4*)(wr + k*8);
    f32x4 a = *(const f32x4*)(xr + k*8);
    f32x4 b = *(const f32x4*)(xr + k*8 + 4);
    f32x4 w0, w1;
    w0[0]=blo(u[0]); w0[1]=bhi(u[0]); w0[2]=blo(u[1]); w0[3]=bhi(u[1]);
    w1[0]=blo(u[2]); w1[1]=bhi(u[2]); w1[2]=blo(u[3]); w1[3]=bhi(u[3]);
    accA += w0*a; accB += w1*b;
  }
  f32x4 s = accA + accB;
  return s[0]+s[1]+s[2]+s[3];
}

// ---------------- generic 32x32 tiled transpose ----------------
__global__ __launch_bounds__(256, 1) void transpose_k(const float* __restrict__ in,
                                                      float* __restrict__ outp, int K, int C){
  __shared__ float tl[32][33];
  int c0 = blockIdx.x * 32, k0 = blockIdx.y * 32;
  int tx = threadIdx.x & 31, ty = threadIdx.x >> 5;
  for (int i = ty; i < 32; i += 8){
    int k = k0 + i, c = c0 + tx;
    if (k < K && c < C) tl[i][tx] = in[k * C + c];
  }
  __syncthreads();
  for (int i = ty; i < 32; i += 8){
    int c = c0 + i, k = k0 + tx;
    if (c < C && k < K) outp[c * K + k] = tl[tx][i];
  }
}

// ---------------- M1 = projW @ d1Wi  (512x768) ----------------
__global__ __launch_bounds__(128, 1) void fuse_k(const float* __restrict__ projW,
    const float* __restrict__ d1Wi, float* __restrict__ M1){
  int jt = blockIdx.x % 6, i = blockIdx.x / 6;
  int j = jt * 128 + threadIdx.x;
  float acc = 0.f;
  for (int k = 0; k < 256; ++k) acc += projW[i*256+k] * d1Wi[k*768+j];
  M1[i*768+j] = acc;
}

// ---------------- c1 = projB @ d1Wi + d1Bi ----------------
__global__ __launch_bounds__(256, 1) void c1_k(const float* __restrict__ projB,
    const float* __restrict__ d1Wi, const float* __restrict__ d1Bi, float* __restrict__ C1){
  int j = blockIdx.x * 256 + threadIdx.x;
  float acc = d1Bi[j];
  for (int k = 0; k < 256; ++k) acc += projB[k] * d1Wi[k*768+j];
  C1[j] = acc;
}

// ---------------- pack per-sl bf16 weight blobs ----------------
__global__ __launch_bounds__(512, 1) void pack_k(float* __restrict__ ws){
  int sl = blockIdx.x;
  const float* TAI = ws + T_WIT_A;
  const float* TAH = ws + T_WHT_A;
  const float* TM1 = ws + T_M1T;
  const float* TH1 = ws + T_WHT1;
  const float* TPJ = ws + T_PJT;
  const float* TI2 = ws + T_WIT2;
  const float* TH2 = ws + T_WHT2;
  const float* TQ  = ws + T_QWT;
  unsigned short* blob = (unsigned short*)(ws + OFF_BLOB) + (size_t)sl * BLOB_STR;
  for (int idx = threadIdx.x; idx < BLOB_N; idx += 512){
    float v; int cs, k, o;
    if (idx < BO_AH){ cs = idx / 384; k = idx - cs*384;
      v = TAI[((cs%3)*256 + sl*4 + cs/3)*384 + k]; }
    else if (idx < BO_Q){ o = idx - BO_AH; cs = o >> 8; k = o & 255;
      v = TAH[((cs%3)*256 + sl*4 + cs/3)*256 + k]; }
    else if (idx < BO_M1){ o = idx - BO_Q; cs = o >> 8; k = o & 255;
      v = TQ[(sl*4 + cs)*256 + k]; }
    else if (idx < BO_H1){ o = idx - BO_M1; cs = o >> 9; k = o & 511;
      v = TM1[((cs%3)*256 + sl*4 + cs/3)*512 + k]; }
    else if (idx < BO_PJ){ o = idx - BO_H1; cs = o >> 8; k = o & 255;
      v = TH1[((cs%3)*256 + sl*4 + cs/3)*256 + k]; }
    else if (idx < BO_I2){ o = idx - BO_PJ; cs = o >> 9; k = o & 511;
      v = TPJ[(sl*4 + cs)*512 + k]; }
    else if (idx < BO_H2){ o = idx - BO_I2; cs = o >> 8; k = o & 255;
      v = TI2[((cs%3)*256 + sl*4 + cs/3)*256 + k]; }
    else { o = idx - BO_H2; cs = o >> 8; k = o & 255;
      v = TH2[((cs%3)*256 + sl*4 + cs/3)*256 + k]; }
    blob[idx] = f2bf(v);
  }
}

// ---------------- QT: coalesced bf16 qW^T copy into out's gate region ----------------
// layout [k/8][j][8]: reader lane j at iter it reads qtb[it*2048 + j*8 .. +8)
__global__ __launch_bounds__(256, 1) void qt_k(const float* __restrict__ ws,
                                               float* __restrict__ out){
  unsigned short* qtb = (unsigned short*)(out + GOFF);
  const float* TQ = ws + T_QWT;
  int idx = blockIdx.x * 256 + threadIdx.x;   // 65536 total
  int it = idx >> 11, j = (idx >> 3) & 255, e = idx & 7;
  qtb[idx] = f2bf(TQ[j*256 + it*8 + e]);
}

// ---------------- prenet: bf16 output ----------------
__global__ __launch_bounds__(NTH, 1) void prenet_k(float* __restrict__ ws,
    const float* __restrict__ inp, const float* __restrict__ W1, const float* __restrict__ B1,
    const float* __restrict__ W2, const float* __restrict__ B2){
  __shared__ float xT[160 * 33];
  __shared__ float hT[256 * 33];
  int t = blockIdx.x, half = blockIdx.y, tid = threadIdx.x;
  int bbase = half * 32;
  for (int r = tid; r < 32 * 160; r += NTH){
    int b2 = r / 160; int k = r - b2 * 160;
    xT[k * 33 + b2] = (t == 0) ? 0.f : inp[((bbase + b2) * TDEC + (t - 1)) * 160 + k];
  }
  __syncthreads();
  int bl = tid & 31, slot = tid >> 5;
  float acc1[16];
  #pragma unroll
  for (int i = 0; i < 16; ++i) acc1[i] = 0.f;
  for (int k = 0; k < 160; ++k){
    float xv = xT[k * 33 + bl];
    const float* wr = W1 + k * 256 + slot * 16;
    #pragma unroll
    for (int i = 0; i < 16; ++i) acc1[i] += xv * wr[i];
  }
  #pragma unroll
  for (int i = 0; i < 16; ++i){
    int c = slot * 16 + i;
    hT[c * 33 + bl] = fmaxf(acc1[i] + B1[c], 0.f);
  }
  __syncthreads();
  float acc2[8];
  #pragma unroll
  for (int i = 0; i < 8; ++i) acc2[i] = 0.f;
  for (int k = 0; k < 256; ++k){
    float hv = hT[k * 33 + bl];
    const float* wr = W2 + k * 128 + slot * 8;
    #pragma unroll
    for (int i = 0; i < 8; ++i) acc2[i] += hv * wr[i];
  }
  unsigned short* dst = (unsigned short*)(ws + OFF_PRE) + (size_t)t*8192 + (bbase + bl)*128 + slot*8;
  u32x4 pk;
  #pragma unroll
  for (int i = 0; i < 4; ++i){
    float v0 = fmaxf(acc2[2*i] + B2[slot*8 + 2*i], 0.f);
    float v1 = fmaxf(acc2[2*i+1] + B2[slot*8 + 2*i+1], 0.f);
    pk[i] = (unsigned)f2bf(v0) | ((unsigned)f2bf(v1) << 16);
  }
  *(u32x4*)dst = pk;
}

// ---------------- processed_memory (bf16) + enc bf16 copy ----------------
__global__ __launch_bounds__(NTH, 1) void pm_k(float* __restrict__ ws,
    const float* __restrict__ enc, const float* __restrict__ memW){
  int wg = blockIdx.x, tid = threadIdx.x;
  int b = wg & 63, th = wg >> 6;
  int slot = tid & 7, tt = tid >> 3;
  int trow = th * 64 + tt;
  const float* er = enc + ((size_t)(b * 512 + trow)) * 256;
  f32x4 acc[8];
  #pragma unroll
  for (int i = 0; i < 8; ++i) acc[i] = 0.f;
  for (int k = 0; k < 256; ++k){
    float ev = er[k];
    const f32x4* wr = (const f32x4*)(memW + k * 256 + slot * 32);
    #pragma unroll
    for (int i = 0; i < 8; ++i) acc[i] += ev * wr[i];
  }
  unsigned short* pmB = (unsigned short*)(ws + OFF_PMB);
  unsigned short* dst = pmB + ((size_t)(b * 512 + trow)) * 256 + slot * 32;
  #pragma unroll
  for (int i = 0; i < 8; ++i){
    u32x2 pk;
    pk[0] = (unsigned)f2bf(acc[i][0]) | ((unsigned)f2bf(acc[i][1]) << 16);
    pk[1] = (unsigned)f2bf(acc[i][2]) | ((unsigned)f2bf(acc[i][3]) << 16);
    *(u32x2*)(dst + i * 4) = pk;
  }
  const float* e2 = enc + ((size_t)(b * 512 + th * 64)) * 256;
  unsigned* eb = (unsigned*)((unsigned short*)(ws + OFF_ENCB) + ((size_t)(b * 512 + th * 64)) * 256);
  for (int i = tid; i < 64 * 128; i += NTH){
    float v0 = e2[i * 2], v1 = e2[i * 2 + 1];
    eb[i] = (unsigned)f2bf(v0) | ((unsigned)f2bf(v1) << 16);
  }
}

// ---------------- persistent recurrent decoder ----------------
// 512 WGs = 8 independent groups x 64 WGs; group g owns batches 8g..8g+7.
// 2 WGs/CU from different groups overlap each other's barrier waits.
// Per WG: 8 batches, K-split GRU dots combined via shfl_xor(.,8) (tid bit 3).
// pm/enc slices in registers; q recomputed per-WG from coalesced QT.
__global__ __launch_bounds__(NTH, 2) void decoder_k(
    float* __restrict__ ws, float* __restrict__ out,
    const int* __restrict__ memlen,
    const float* __restrict__ vW,
    const float* __restrict__ attBi, const float* __restrict__ attBh,
    const float* __restrict__ projB,
    const float* __restrict__ d1Bh,
    const float* __restrict__ d2Bi, const float* __restrict__ d2Bh)
{
  const int wg = blockIdx.x, tid = threadIdx.x;
  int* bar = (int*)ws;
  float* attH = ws + OFF_ATTH;       // [2][64][256]
  float* h1a  = ws + OFF_H1;
  float* h2a  = ws + OFF_H2;
  float* const curB[2]  = { ws + OFF_CURP, ws + OFF_Q };    // ctx partial-sum buffers
  float* const attSB[2] = { ws + OFF_ATTS, ws + OFF_ATTS + 64 };
  float* d1v  = ws + OFF_D1;
  const float* C1v = ws + OFF_C1;
  const unsigned short* preB16 = (const unsigned short*)(ws + OFF_PRE);
  const unsigned short* pmB  = (const unsigned short*)(ws + OFF_PMB);
  const unsigned short* encB = (const unsigned short*)(ws + OFF_ENCB);
  const unsigned short* qtb = (const unsigned short*)(out + GOFF);
  float* d2a  = ws + OFF_D2A;

  __shared__ float BUF[6208];
  __shared__ float qL[256], vL[256];
  __shared__ float eL[64];
  __shared__ float ewGi[96], ewGh[96], pdec[32];

  if (tid < 256) vL[tid] = vW[tid];

  // group decomposition: g owns batches [g*8, g*8+8)
  const int g = wg >> 6, l = wg & 63;
  const int sl = l;                       // GRU slice 0..63 (j = sl*4..+4)
  const int b0 = g << 3;                  // batch base
  const int b2 = b0 + (l >> 3), ch2 = l & 7;   // attention batch / enc chunk (64 rows)
  const int len2 = memlen[b2];
  const unsigned short* blob = (const unsigned short*)(ws + OFF_BLOB) + (size_t)sl * BLOB_STR;

  const int bq = tid & 7, x = tid >> 3;           // batch-within-group / role slot
  const int r0 = tid >> 6, c0 = (tid & 63) << 2;  // gather mapping (8 rows x 256)
  const int prr = tid >> 4, pcc = (tid & 15) * 8; // prenet unpack (tid<128)

  // role constants: x<24 -> Gi half (cs=x>>1, kh=x&1); x in 24..47 -> Gh half;
  // x>=48 -> proj quarter-dots (P4 only). Per-role biases hoisted to regs.
  int cs = 0, kh = 0;
  if (x < 24){ cs = x >> 1; kh = x & 1; }
  else if (x < 48){ cs = (x - 24) >> 1; kh = x & 1; }
  float rb0 = 0.f, rb1 = 0.f, rb2 = 0.f;
  if (x < 48 && kh == 0){
    int gg2 = cs % 3, jh2 = cs / 3;
    int col = gg2*256 + sl*4 + jh2;
    if (x < 24){ rb0 = attBi[col]; rb1 = C1v[col];  rb2 = d2Bi[col]; }
    else       { rb0 = attBh[col]; rb1 = d1Bh[col]; rb2 = d2Bh[col]; }
  }
  const float pjB = (tid < 32) ? projB[sl*4 + (tid>>3)] : 0.f;

  // ---- persistent register staging of this thread's pm/enc slices ----
  // pm: thread (te=tid>>3, part=tid&7) -> row ch2*64+te, k-range part*32..+32
  // enc: thread (ich=tid>>6, dd=tid&63) -> rows ch2*64+ich*8..+8, dims dd*4..+4
  u32x4 pmv[4]; u32x2 env2[8];
  {
    int te = tid >> 3, part = tid & 7;
    const u32x4* pmp = (const u32x4*)(pmB + ((size_t)(b2*512 + ch2*64 + te))*256 + part*32);
    #pragma unroll
    for (int i = 0; i < 4; ++i) pmv[i] = pmp[i];
    int ich = tid >> 6, dd = tid & 63;
    const unsigned short* ep = encB + ((size_t)(b2*512 + ch2*64 + ich*8))*256 + dd*4;
    #pragma unroll
    for (int i = 0; i < 8; ++i) env2[i] = *(const u32x2*)(ep + i*256);
  }

  // ---- initial prefetch of P0 inputs for t=0 (rb=1 buffers; all zeroed) ----
  f32x4 pH, pC;
  float pS;
  u32x4 ppre = 0u;
  {
    pH = cload16(attH + 16384 + (b0+r0)*256 + c0);
    pC = cload16(curB[1] + (b0+r0)*256 + c0);
    pS = aload4(attSB[1] + b0 + r0);
    if (tid < 128) ppre = cload16u(preB16 + (b0 + prr)*128 + pcc);
  }

  int bn = 0;
  for (int t = 0; t < TDEC; ++t){
    const int w = t & 1, rb = w ^ 1;

    // ===== P0: attention GRU: h' = GRU(cat(pre, ctx_{t-1}), att_h) =====
    {
      float* xL = BUF;              // [8][388]: [0:128)=pre, [128:384)=ctx
      float* hL = BUF + 3104;       // [8][260]: att_h prev
      asm volatile("s_waitcnt vmcnt(0)" : "+v"(pH),"+v"(pC),"+v"(ppre));
      float iv = pS > 0.f ? 1.f/pS : 0.f;
      if (tid < 128){
        float* xd = xL + prr*388 + pcc;
        xd[0]=blo(ppre[0]); xd[1]=bhi(ppre[0]); xd[2]=blo(ppre[1]); xd[3]=bhi(ppre[1]);
        xd[4]=blo(ppre[2]); xd[5]=bhi(ppre[2]); xd[6]=blo(ppre[3]); xd[7]=bhi(ppre[3]);
      }
      *(f32x4*)(hL + r0*260 + c0) = pH;
      *(f32x4*)(xL + r0*388 + 128 + c0) = pC*iv;
      // zero this step's ctx/attS accumulators (buffer w; last read 3 bars ago)
      if (tid < 32) astore4(curB[w] + wg*32 + tid, 0.f);
      if (l == 0 && tid < 8) astore4(attSB[w] + b0 + tid, 0.f);
      ldsbar();
      {
        float acc = 0.f;
        if (x < 24)       acc = bdot<24>(blob + BO_AI + cs*384 + kh*192, xL + bq*388 + kh*192);
        else if (x < 48)  acc = bdot<16>(blob + BO_AH + cs*256 + kh*128, hL + bq*260 + kh*128);
        if (x < 48){
          acc += __shfl_xor(acc, 8);
          if (kh == 0) (x < 24 ? ewGi : ewGh)[cs*8 + bq] = acc + rb0;
        }
      }
      ldsbar();
      if (tid < 32){
        int bt = tid & 7, jj = tid >> 3;
        int j = sl*4 + jj;
        float ir = ewGi[(jj*3+0)*8+bt] + ewGh[(jj*3+0)*8+bt];
        float iz = ewGi[(jj*3+1)*8+bt] + ewGh[(jj*3+1)*8+bt];
        float inn = ewGi[(jj*3+2)*8+bt];
        float hn  = ewGh[(jj*3+2)*8+bt];
        float rg = fsig(ir), z = fsig(iz);
        float n = ftanh(inn + rg * hn);
        float h = hL[bt*260 + j];
        astore4(attH + w*16384 + (b0+bt)*256 + j, (1.f - z)*n + z*h);
      }
    }
    gbar(bar, g, l, ++bn);

    // ===== P2: q (coalesced QT) + scoring + exp + partial sum/context =====
    {
      float* ctxP = BUF;            // [8][256]
      float* qIn  = BUF + 2560;     // [256] att_h' row for this WG's batch
      if (tid < 64){
        f32x4 v = cload16w(attH + w*16384 + b2*256 + tid*4);
        *(f32x4*)(qIn + tid*4) = v;
      }
      ldsbar();
      if (tid < 256){
        const unsigned short* qw = qtb + tid*8;
        f32x4 aA = 0.f, aB = 0.f;
        #pragma unroll 4
        for (int it = 0; it < 32; ++it){
          u32x4 u = *(const u32x4*)(qw + (size_t)it*2048);
          f32x4 a = *(const f32x4*)(qIn + it*8);
          f32x4 b = *(const f32x4*)(qIn + it*8 + 4);
          f32x4 w0, w1;
          w0[0]=blo(u[0]); w0[1]=bhi(u[0]); w0[2]=blo(u[1]); w0[3]=bhi(u[1]);
          w1[0]=blo(u[2]); w1[1]=bhi(u[2]); w1[2]=blo(u[3]); w1[3]=bhi(u[3]);
          aA += w0*a; aB += w1*b;
        }
        f32x4 s4 = aA + aB;
        qL[tid] = s4[0]+s4[1]+s4[2]+s4[3];
      }
      ldsbar();
      {
        int te = tid >> 3, part = tid & 7;
        int ge = ch2*64 + te;
        float a4 = 0.f;
        #pragma unroll
        for (int i = 0; i < 4; ++i){
          u32x4 u = pmv[i];
          int kb = part*32 + i*8;
          a4 += ftanh(blo(u[0]) + qL[kb+0]) * vL[kb+0];
          a4 += ftanh(bhi(u[0]) + qL[kb+1]) * vL[kb+1];
          a4 += ftanh(blo(u[1]) + qL[kb+2]) * vL[kb+2];
          a4 += ftanh(bhi(u[1]) + qL[kb+3]) * vL[kb+3];
          a4 += ftanh(blo(u[2]) + qL[kb+4]) * vL[kb+4];
          a4 += ftanh(bhi(u[2]) + qL[kb+5]) * vL[kb+5];
          a4 += ftanh(blo(u[3]) + qL[kb+6]) * vL[kb+6];
          a4 += ftanh(bhi(u[3]) + qL[kb+7]) * vL[kb+7];
        }
        a4 += __shfl_xor(a4, 1);
        a4 += __shfl_xor(a4, 2);
        a4 += __shfl_xor(a4, 4);
        float e = (ge < len2) ? __expf(a4) : 0.f;
        if (part == 0){
          eL[te] = e;
          out[AOFF + ((size_t)(b2*TDEC + t))*512 + ge] = e;
        }
      }
      ldsbar();
      if (tid < 64){
        float s = eL[tid];
        #pragma unroll
        for (int o = 32; o > 0; o >>= 1) s += __shfl_down(s, o);
        if (tid == 0) aadd(attSB[w] + b2, s);
      }
      {
        int ich = tid >> 6, dd = tid & 63;
        f32x4 ac = 0.f;
        #pragma unroll
        for (int i = 0; i < 8; ++i){
          u32x2 u = env2[i];
          float e = eL[ich*8 + i];
          ac[0] += e*blo(u[0]); ac[1] += e*bhi(u[0]);
          ac[2] += e*blo(u[1]); ac[3] += e*bhi(u[1]);
        }
        *(f32x4*)(ctxP + ich*256 + dd*4) = ac;
      }
      ldsbar();
      if (tid < 256){
        float s = 0.f;
        #pragma unroll
        for (int i = 0; i < 8; ++i) s += ctxP[i*256 + tid];
        aadd(curB[w] + b2*256 + tid, s);
      }
    }
    gbar(bar, g, l, ++bn);

    // ===== P4: GRU1 via fused M1 + decin side-dot; d1 = h1' + decin =====
    {
      float* yL  = BUF;             // [8][516]: [0:256)=att_h', [256:512)=ctxN
      float* h1L = BUF + 4128;      // [8][260]
      f32x4 vA = cload16(attH + w*16384 + (b0+r0)*256 + c0);
      f32x4 vH = cload16(h1a + rb*16384 + (b0+r0)*256 + c0);
      f32x4 vC = cload16(curB[w] + (b0+r0)*256 + c0);
      float s0 = aload4(attSB[w] + b0 + r0);
      asm volatile("s_waitcnt vmcnt(0)" : "+v"(vA),"+v"(vH),"+v"(vC));
      float iv = s0 > 0.f ? 1.f/s0 : 0.f;
      *(f32x4*)(yL + r0*516 + c0) = vA;
      *(f32x4*)(h1L + r0*260 + c0) = vH;
      *(f32x4*)(yL + r0*516 + 256 + c0) = vC*iv;
      ldsbar();
      {
        float acc = 0.f;
        if (x < 24)       acc = bdot<32>(blob + BO_M1 + cs*512 + kh*256, yL + bq*516 + kh*256);
        else if (x < 48)  acc = bdot<16>(blob + BO_H1 + cs*256 + kh*128, h1L + bq*260 + kh*128);
        else {
          int idx = x - 48, cc = idx >> 2, qq = idx & 3;
          acc = bdot<16>(blob + BO_PJ + cc*512 + qq*128, yL + bq*516 + qq*128);
          acc += __shfl_xor(acc, 8);
          acc += __shfl_xor(acc, 16);
          if (qq == 0) pdec[cc*8 + bq] = acc;
        }
        if (x < 48){
          acc += __shfl_xor(acc, 8);
          if (kh == 0) (x < 24 ? ewGi : ewGh)[cs*8 + bq] = acc + rb1;
        }
      }
      ldsbar();
      if (tid < 32){
        int bt = tid & 7, jj = tid >> 3;
        int j = sl*4 + jj;
        float ir = ewGi[(jj*3+0)*8+bt] + ewGh[(jj*3+0)*8+bt];
        float iz = ewGi[(jj*3+1)*8+bt] + ewGh[(jj*3+1)*8+bt];
        float inn = ewGi[(jj*3+2)*8+bt];
        float hn  = ewGh[(jj*3+2)*8+bt];
        float rg = fsig(ir), z = fsig(iz);
        float n = ftanh(inn + rg * hn);
        float hv = h1L[bt*260 + j];
        float hnew = (1.f - z)*n + z*hv;
        float dec = pdec[jj*8 + bt] + pjB;
        astore4(h1a + w*16384 + (b0+bt)*256 + j, hnew);
        astore4(d1v + (b0+bt)*256 + j, hnew + dec);
      }
      if (l == 0 && tid < 8)
        ws[OFF_SUMS + t*64 + b0 + tid] = aload4(attSB[w] + b0 + tid);
    }
    gbar(bar, g, l, ++bn);

    // ===== P5: GRU2; d2 = h2' + d1 (feeds outputs only; no group barrier).
    //        Also prefetch next-step P0 inputs (barrier-stable by now). =====
    {
      float* dL  = BUF;             // [8][260]
      float* h2L = BUF + 2080;      // [8][260]
      f32x4 vD = cload16(d1v + (b0+r0)*256 + c0);
      f32x4 vH = cload16(h2a + rb*16384 + (b0+r0)*256 + c0);
      asm volatile("s_waitcnt vmcnt(0)" : "+v"(vD),"+v"(vH));
      {
        // prefetch for P0(t+1): rb(t+1)==w(t) buffers, pre row t+1
        pH = cload16(attH + w*16384 + (b0+r0)*256 + c0);
        pC = cload16(curB[w] + (b0+r0)*256 + c0);
        pS = aload4(attSB[w] + b0 + r0);
        int tn = (t + 1 < TDEC) ? (t + 1) : 0;
        if (tid < 128) ppre = cload16u(preB16 + (size_t)tn*8192 + (b0 + prr)*128 + pcc);
      }
      *(f32x4*)(dL + r0*260 + c0) = vD;
      *(f32x4*)(h2L + r0*260 + c0) = vH;
      ldsbar();
      {
        float acc = 0.f;
        if (x < 24)       acc = bdot<16>(blob + BO_I2 + cs*256 + kh*128, dL + bq*260 + kh*128);
        else if (x < 48)  acc = bdot<16>(blob + BO_H2 + cs*256 + kh*128, h2L + bq*260 + kh*128);
        if (x < 48){
          acc += __shfl_xor(acc, 8);
          if (kh == 0) (x < 24 ? ewGi : ewGh)[cs*8 + bq] = acc + rb2;
        }
      }
      ldsbar();
      if (tid < 32){
        int bt = tid & 7, jj = tid >> 3;
        int j = sl*4 + jj;
        float ir = ewGi[(jj*3+0)*8+bt] + ewGh[(jj*3+0)*8+bt];
        float iz = ewGi[(jj*3+1)*8+bt] + ewGh[(jj*3+1)*8+bt];
        float inn = ewGi[(jj*3+2)*8+bt];
        float hn  = ewGh[(jj*3+2)*8+bt];
        float rg = fsig(ir), z = fsig(iz);
        float n = ftanh(inn + rg * hn);
        float hv = h2L[bt*260 + j];
        float hnew = (1.f - z)*n + z*hv;
        astore4(h2a + w*16384 + (b0+bt)*256 + j, hnew);
        d2a[t*16384 + j*64 + (b0+bt)] = hnew + dL[bt*260 + j];
      }
      ldsbar();  // protect BUF/ew from next-iteration P0 (LDS only; vm stays in flight)
    }
  }
}

// ---------------- alignment rescale ----------------
__global__ __launch_bounds__(NTH, 1) void rescale_k(const float* __restrict__ ws,
                                                    float* __restrict__ out){
  int blk = blockIdx.x;
  int b = blk / TDEC, t = blk - b * TDEC;
  float s = ws[OFF_SUMS + t*64 + b];
  float inv = (s > 0.f) ? 1.f/s : 0.f;
  out[AOFF + (size_t)blk*512 + threadIdx.x] *= inv;
}

// ---------------- deferred mel/gate heads ----------------
__global__ __launch_bounds__(NTH, 1) void outproj_k(const float* __restrict__ ws,
    float* __restrict__ out, const float* __restrict__ melW, const float* __restrict__ melB,
    const float* __restrict__ gateW, const float* __restrict__ gateB){
  int t = blockIdx.x, tid = threadIdx.x;
  int cx = tid & 255, bh = tid >> 8;
  const float* src = ws + OFF_D2A + t*16384 + bh*32;
  float acc[32];
  #pragma unroll
  for (int i = 0; i < 32; ++i) acc[i] = 0.f;
  bool ismel = (cx < 160);
  bool isgate = (cx >= 160 && cx < 162);
  for (int j = 0; j < 256; ++j){
    float wv = 0.f;
    if (ismel) wv = melW[j*160 + cx];
    else if (isgate) wv = gateW[j*2 + (cx - 160)];
    const f32x4* dp = (const f32x4*)(src + j*64);
    f32x4 vv[8];
    #pragma unroll
    for (int q = 0; q < 8; ++q) vv[q] = dp[q];
    #pragma unroll
    for (int q = 0; q < 8; ++q){
      acc[q*4+0] += vv[q][0]*wv; acc[q*4+1] += vv[q][1]*wv;
      acc[q*4+2] += vv[q][2]*wv; acc[q*4+3] += vv[q][3]*wv;
    }
  }
  if (ismel){
    float bb = melB[cx];
    #pragma unroll
    for (int i = 0; i < 32; ++i){
      int b = bh*32 + i;
      out[((size_t)(b*TDEC + t))*160 + cx] = acc[i] + bb;
    }
  } else if (isgate){
    int g = cx - 160;
    float bb = gateB[g];
    #pragma unroll
    for (int i = 0; i < 32; ++i){
      int b = bh*32 + i;
      out[GOFF + ((size_t)(b*TDEC + t))*2 + g] = fsig(acc[i] + bb);
    }
  }
}

extern "C" void kernel_launch(void* const* d_in, const int* in_sizes, int n_in,
                              void* d_out, int out_size, void* d_ws, size_t ws_size,
                              hipStream_t stream)
{
  (void)in_sizes; (void)n_in; (void)out_size; (void)ws_size;
  const float* enc   = (const float*)d_in[0];
  const float* inp   = (const float*)d_in[1];
  const int*   mlen  = (const int*)d_in[2];
  const float* preW1 = (const float*)d_in[3];
  const float* preB1 = (const float*)d_in[4];
  const float* preW2 = (const float*)d_in[5];
  const float* preB2 = (const float*)d_in[6];
  const float* memW  = (const float*)d_in[7];
  const float* qW    = (const float*)d_in[8];
  const float* vW    = (const float*)d_in[9];
  const float* attWi = (const float*)d_in[10];
  const float* attWh = (const float*)d_in[11];
  const float* attBi = (const float*)d_in[12];
  const float* attBh = (const float*)d_in[13];
  const float* projW = (const float*)d_in[14];
  const float* projB = (const float*)d_in[15];
  const float* d1Wi  = (const float*)d_in[16];
  const float* d1Wh  = (const float*)d_in[17];
  const float* d1Bi  = (const float*)d_in[18];
  const float* d1Bh  = (const float*)d_in[19];
  const float* d2Wi  = (const float*)d_in[20];
  const float* d2Wh  = (const float*)d_in[21];
  const float* d2Bi  = (const float*)d_in[22];
  const float* d2Bh  = (const float*)d_in[23];
  const float* melW  = (const float*)d_in[24];
  const float* melB  = (const float*)d_in[25];
  const float* gateW = (const float*)d_in[26];
  const float* gateB = (const float*)d_in[27];
  float* ws = (float*)d_ws;
  float* out = (float*)d_out;

  hipMemsetAsync(d_ws, 0, (size_t)ZERO_FLOATS * sizeof(float), stream);

  dim3 tt(256);
  transpose_k<<<dim3(24, 12), tt, 0, stream>>>(attWi, ws + T_WIT_A, 384, 768);
  transpose_k<<<dim3(24, 8),  tt, 0, stream>>>(attWh, ws + T_WHT_A, 256, 768);
  transpose_k<<<dim3(24, 8),  tt, 0, stream>>>(d1Wh,  ws + T_WHT1, 256, 768);
  transpose_k<<<dim3(24, 8),  tt, 0, stream>>>(d2Wi,  ws + T_WIT2, 256, 768);
  transpose_k<<<dim3(24, 8),  tt, 0, stream>>>(d2Wh,  ws + T_WHT2, 256, 768);
  transpose_k<<<dim3(8, 16),  tt, 0, stream>>>(projW, ws + T_PJT, 512, 256);
  transpose_k<<<dim3(8, 8),   tt, 0, stream>>>(qW,    ws + T_QWT, 256, 256);
  fuse_k<<<3072, 128, 0, stream>>>(projW, d1Wi, ws + T_M1);
  c1_k<<<3, 256, 0, stream>>>(projB, d1Wi, d1Bi, ws + OFF_C1);
  transpose_k<<<dim3(24, 16), tt, 0, stream>>>(ws + T_M1, ws + T_M1T, 512, 768);
  pack_k<<<64, NTH, 0, stream>>>(ws);
  qt_k<<<256, 256, 0, stream>>>(ws, out);

  prenet_k<<<dim3(TDEC, 2), NTH, 0, stream>>>(ws, inp, preW1, preB1, preW2, preB2);
  pm_k<<<512, NTH, 0, stream>>>(ws, enc, memW);
  decoder_k<<<NWG, NTH, 0, stream>>>(ws, out, mlen, vW, attBi, attBh, projB,
                                     d1Bh, d2Bi, d2Bh);
  rescale_k<<<64 * TDEC, NTH, 0, stream>>>(ws, out);
  outproj_k<<<TDEC, NTH, 0, stream>>>(ws, out, melW, melB, gateW, gateB);
}

// Round 5
// 13210.716 us; speedup vs baseline: 1.3064x; 1.3064x over previous
//
#include <hip/hip_runtime.h>

#define TDEC 400
#define NTH 512
#define NWG 256

typedef float f32x4 __attribute__((ext_vector_type(4)));
typedef unsigned u32x4 __attribute__((ext_vector_type(4)));
typedef unsigned u32x2 __attribute__((ext_vector_type(2)));

// ---------------- ws layout (float offsets) ----------------
#define OFF_BAR   0
#define OFF_ATTH  11264
#define OFF_H1    44032
#define OFF_H2    76800
#define OFF_CURP  109568       /* ctx buffer parity 0 [64][256] */
#define OFF_ATTS  125952       /* attS [2][64] */
#define OFF_Q     126208       /* ctx buffer parity 1 [64][256] */
#define ZERO_FLOATS 142592     /* memset covers BAR..Q inclusive */
#define OFF_D1    142592
#define OFF_SUMS  158976
#define OFF_C1    184576
#define OFF_PRE   185600       /* bf16 [400][64][128] */
#define OFF_PMB   1824000      /* bf16 [64][512][256] */
#define OFF_ENCB  6018304      /* bf16 [64][512][256] */
#define OFF_D2A   10212608     /* fp32 [400][256][64]; setup overlays below */
#define T_WIT_A   10212608
#define T_WHT_A   10507520
#define T_M1T     10704128
#define T_WHT1    11097344
#define T_PJT     11293952
#define T_WIT2    11425024
#define T_WHT2    11621632
#define T_QWT     11818240
#define T_M1      11883776
#define OFF_BLOB  16766208     /* bf16: 64 slices x BLOB_STR */
// total 17,618,176 floats = 70.5 MB

#define BLOB_N   26112
#define BLOB_STR 26624
// blob section offsets (ushort units)
#define BO_AI  0
#define BO_AH  4608
#define BO_Q   7680
#define BO_M1  8704
#define BO_H1  14848
#define BO_PJ  17920
#define BO_I2  19968
#define BO_H2  23040

#define AOFF 4096000
#define GOFF 17203200          /* gates region; doubles as QT scratch during decoder */

// group-local barrier counter slots (int offsets); group g adds +g*64
#define MSTI  (8*1024)
#define GENI  (9*1024)
#define FAILI (10*1024)

__device__ __forceinline__ float fsig(float x){ return 1.0f/(1.0f+__expf(-x)); }
__device__ __forceinline__ float ftanh(float x){ float e = __expf(2.0f*x); return 1.0f - 2.0f/(e+1.0f); }
__device__ __forceinline__ float blo(unsigned u){ return __uint_as_float(u<<16); }
__device__ __forceinline__ float bhi(unsigned u){ return __uint_as_float(u & 0xffff0000u); }

__device__ __forceinline__ f32x4 cload16(const float* p){
  f32x4 r;
  asm volatile("global_load_dwordx4 %0, %1, off sc0 sc1" : "=v"(r) : "v"(p));
  return r;
}
__device__ __forceinline__ f32x4 cload16w(const float* p){
  f32x4 r;
  asm volatile("global_load_dwordx4 %0, %1, off sc0 sc1\n\ts_waitcnt vmcnt(0)" : "=v"(r) : "v"(p));
  return r;
}
__device__ __forceinline__ u32x4 cload16u(const unsigned short* p){
  u32x4 r;
  asm volatile("global_load_dwordx4 %0, %1, off sc0 sc1" : "=v"(r) : "v"(p));
  return r;
}
__device__ __forceinline__ float aload4(const float* p){
  unsigned u = __hip_atomic_load((const unsigned*)p, __ATOMIC_RELAXED, __HIP_MEMORY_SCOPE_AGENT);
  return __uint_as_float(u);
}
__device__ __forceinline__ void astore4(float* p, float v){
  __hip_atomic_store((unsigned*)p, __float_as_uint(v), __ATOMIC_RELAXED, __HIP_MEMORY_SCOPE_AGENT);
}
__device__ __forceinline__ void aadd(float* p, float v){
  __hip_atomic_fetch_add(p, v, __ATOMIC_RELAXED, __HIP_MEMORY_SCOPE_AGENT);
}
__device__ __forceinline__ int aloadi(const int* p){
  return __hip_atomic_load(p, __ATOMIC_RELAXED, __HIP_MEMORY_SCOPE_AGENT);
}

// LDS-only barrier: does NOT drain vmcnt (global stores/prefetches stay in
// flight; gbar's vmcnt(0) provides cross-WG visibility).
__device__ __forceinline__ void ldsbar(){
  __builtin_amdgcn_sched_barrier(0);
  asm volatile("s_waitcnt lgkmcnt(0)" ::: "memory");
  __builtin_amdgcn_s_barrier();
  __builtin_amdgcn_sched_barrier(0);
}

// group-local (64-WG) fence-free barrier: monotonic counters, relaxed agent
// atomics. 8 arrival counters x 8 arrivals per round, per group.
__device__ __forceinline__ void gbar(int* bar, int g, int l, int n){
  asm volatile("s_waitcnt vmcnt(0)" ::: "memory");
  __syncthreads();
  if (threadIdx.x == 0){
    if (aloadi(&bar[FAILI]) == 0){
      int a = __hip_atomic_fetch_add(&bar[(l&7)*1024 + g*64], 1, __ATOMIC_RELAXED, __HIP_MEMORY_SCOPE_AGENT);
      if (a == 8*n - 1){
        int m = __hip_atomic_fetch_add(&bar[MSTI + g*64], 1, __ATOMIC_RELAXED, __HIP_MEMORY_SCOPE_AGENT);
        if (m == 8*n - 1)
          __hip_atomic_store(&bar[GENI + g*64], n, __ATOMIC_RELAXED, __HIP_MEMORY_SCOPE_AGENT);
      }
      int sp = 0;
      while (aloadi(&bar[GENI + g*64]) < n){
        __builtin_amdgcn_s_sleep(1);
        if (++sp > (1<<20)){
          __hip_atomic_store(&bar[FAILI], 1, __ATOMIC_RELAXED, __HIP_MEMORY_SCOPE_AGENT);
          break;
        }
      }
    }
  }
  __syncthreads();
}

__device__ __forceinline__ unsigned short f2bf(float f){
  unsigned u = __float_as_uint(f);
  return (unsigned short)((u + 0x7fffu + ((u>>16)&1u)) >> 16);
}

// bf16-weight dot with dual f32x4 accumulators (8x ILP vs scalar acc chain)
template<int N8>
__device__ __forceinline__ float bdot(const unsigned short* wr, const float* xr){
  f32x4 accA = 0.f, accB = 0.f;
  #pragma unroll 4
  for (int k = 0; k < N8; ++k){
    u32x4 u = *(const u32x4*)(wr + k*8);
    f32x4 a = *(const f32x4*)(xr + k*8);
    f32x4 b = *(const f32x4*)(xr + k*8 + 4);
    f32x4 w0, w1;
    w0[0]=blo(u[0]); w0[1]=bhi(u[0]); w0[2]=blo(u[1]); w0[3]=bhi(u[1]);
    w1[0]=blo(u[2]); w1[1]=bhi(u[2]); w1[2]=blo(u[3]); w1[3]=bhi(u[3]);
    accA += w0*a; accB += w1*b;
  }
  f32x4 s = accA + accB;
  return s[0]+s[1]+s[2]+s[3];
}

// ---------------- generic 32x32 tiled transpose ----------------
__global__ __launch_bounds__(256, 1) void transpose_k(const float* __restrict__ in,
                                                      float* __restrict__ outp, int K, int C){
  __shared__ float tl[32][33];
  int c0 = blockIdx.x * 32, k0 = blockIdx.y * 32;
  int tx = threadIdx.x & 31, ty = threadIdx.x >> 5;
  for (int i = ty; i < 32; i += 8){
    int k = k0 + i, c = c0 + tx;
    if (k < K && c < C) tl[i][tx] = in[k * C + c];
  }
  __syncthreads();
  for (int i = ty; i < 32; i += 8){
    int c = c0 + i, k = k0 + tx;
    if (c < C && k < K) outp[c * K + k] = tl[tx][i];
  }
}

// ---------------- M1 = projW @ d1Wi  (512x768) ----------------
__global__ __launch_bounds__(128, 1) void fuse_k(const float* __restrict__ projW,
    const float* __restrict__ d1Wi, float* __restrict__ M1){
  int jt = blockIdx.x % 6, i = blockIdx.x / 6;
  int j = jt * 128 + threadIdx.x;
  float acc = 0.f;
  for (int k = 0; k < 256; ++k) acc += projW[i*256+k] * d1Wi[k*768+j];
  M1[i*768+j] = acc;
}

// ---------------- c1 = projB @ d1Wi + d1Bi ----------------
__global__ __launch_bounds__(256, 1) void c1_k(const float* __restrict__ projB,
    const float* __restrict__ d1Wi, const float* __restrict__ d1Bi, float* __restrict__ C1){
  int j = blockIdx.x * 256 + threadIdx.x;
  float acc = d1Bi[j];
  for (int k = 0; k < 256; ++k) acc += projB[k] * d1Wi[k*768+j];
  C1[j] = acc;
}

// ---------------- pack per-sl bf16 weight blobs ----------------
__global__ __launch_bounds__(512, 1) void pack_k(float* __restrict__ ws){
  int sl = blockIdx.x;
  const float* TAI = ws + T_WIT_A;
  const float* TAH = ws + T_WHT_A;
  const float* TM1 = ws + T_M1T;
  const float* TH1 = ws + T_WHT1;
  const float* TPJ = ws + T_PJT;
  const float* TI2 = ws + T_WIT2;
  const float* TH2 = ws + T_WHT2;
  const float* TQ  = ws + T_QWT;
  unsigned short* blob = (unsigned short*)(ws + OFF_BLOB) + (size_t)sl * BLOB_STR;
  for (int idx = threadIdx.x; idx < BLOB_N; idx += 512){
    float v; int cs, k, o;
    if (idx < BO_AH){ cs = idx / 384; k = idx - cs*384;
      v = TAI[((cs%3)*256 + sl*4 + cs/3)*384 + k]; }
    else if (idx < BO_Q){ o = idx - BO_AH; cs = o >> 8; k = o & 255;
      v = TAH[((cs%3)*256 + sl*4 + cs/3)*256 + k]; }
    else if (idx < BO_M1){ o = idx - BO_Q; cs = o >> 8; k = o & 255;
      v = TQ[(sl*4 + cs)*256 + k]; }
    else if (idx < BO_H1){ o = idx - BO_M1; cs = o >> 9; k = o & 511;
      v = TM1[((cs%3)*256 + sl*4 + cs/3)*512 + k]; }
    else if (idx < BO_PJ){ o = idx - BO_H1; cs = o >> 8; k = o & 255;
      v = TH1[((cs%3)*256 + sl*4 + cs/3)*256 + k]; }
    else if (idx < BO_I2){ o = idx - BO_PJ; cs = o >> 9; k = o & 511;
      v = TPJ[(sl*4 + cs)*512 + k]; }
    else if (idx < BO_H2){ o = idx - BO_I2; cs = o >> 8; k = o & 255;
      v = TI2[((cs%3)*256 + sl*4 + cs/3)*256 + k]; }
    else { o = idx - BO_H2; cs = o >> 8; k = o & 255;
      v = TH2[((cs%3)*256 + sl*4 + cs/3)*256 + k]; }
    blob[idx] = f2bf(v);
  }
}

// ---------------- QT: coalesced bf16 qW^T copy into out's gate region ----------------
// layout [k/8][j][8]: reader lane j at iter it reads qtb[it*2048 + j*8 .. +8)
__global__ __launch_bounds__(256, 1) void qt_k(const float* __restrict__ ws,
                                               float* __restrict__ out){
  unsigned short* qtb = (unsigned short*)(out + GOFF);
  const float* TQ = ws + T_QWT;
  int idx = blockIdx.x * 256 + threadIdx.x;   // 65536 total
  int it = idx >> 11, j = (idx >> 3) & 255, e = idx & 7;
  qtb[idx] = f2bf(TQ[j*256 + it*8 + e]);
}

// ---------------- prenet: bf16 output ----------------
__global__ __launch_bounds__(NTH, 1) void prenet_k(float* __restrict__ ws,
    const float* __restrict__ inp, const float* __restrict__ W1, const float* __restrict__ B1,
    const float* __restrict__ W2, const float* __restrict__ B2){
  __shared__ float xT[160 * 33];
  __shared__ float hT[256 * 33];
  int t = blockIdx.x, half = blockIdx.y, tid = threadIdx.x;
  int bbase = half * 32;
  for (int r = tid; r < 32 * 160; r += NTH){
    int b2 = r / 160; int k = r - b2 * 160;
    xT[k * 33 + b2] = (t == 0) ? 0.f : inp[((bbase + b2) * TDEC + (t - 1)) * 160 + k];
  }
  __syncthreads();
  int bl = tid & 31, slot = tid >> 5;
  float acc1[16];
  #pragma unroll
  for (int i = 0; i < 16; ++i) acc1[i] = 0.f;
  for (int k = 0; k < 160; ++k){
    float xv = xT[k * 33 + bl];
    const float* wr = W1 + k * 256 + slot * 16;
    #pragma unroll
    for (int i = 0; i < 16; ++i) acc1[i] += xv * wr[i];
  }
  #pragma unroll
  for (int i = 0; i < 16; ++i){
    int c = slot * 16 + i;
    hT[c * 33 + bl] = fmaxf(acc1[i] + B1[c], 0.f);
  }
  __syncthreads();
  float acc2[8];
  #pragma unroll
  for (int i = 0; i < 8; ++i) acc2[i] = 0.f;
  for (int k = 0; k < 256; ++k){
    float hv = hT[k * 33 + bl];
    const float* wr = W2 + k * 128 + slot * 8;
    #pragma unroll
    for (int i = 0; i < 8; ++i) acc2[i] += hv * wr[i];
  }
  unsigned short* dst = (unsigned short*)(ws + OFF_PRE) + (size_t)t*8192 + (bbase + bl)*128 + slot*8;
  u32x4 pk;
  #pragma unroll
  for (int i = 0; i < 4; ++i){
    float v0 = fmaxf(acc2[2*i] + B2[slot*8 + 2*i], 0.f);
    float v1 = fmaxf(acc2[2*i+1] + B2[slot*8 + 2*i+1], 0.f);
    pk[i] = (unsigned)f2bf(v0) | ((unsigned)f2bf(v1) << 16);
  }
  *(u32x4*)dst = pk;
}

// ---------------- processed_memory (bf16) + enc bf16 copy ----------------
__global__ __launch_bounds__(NTH, 1) void pm_k(float* __restrict__ ws,
    const float* __restrict__ enc, const float* __restrict__ memW){
  int wg = blockIdx.x, tid = threadIdx.x;
  int b = wg & 63, th = wg >> 6;
  int slot = tid & 7, tt = tid >> 3;
  int trow = th * 64 + tt;
  const float* er = enc + ((size_t)(b * 512 + trow)) * 256;
  f32x4 acc[8];
  #pragma unroll
  for (int i = 0; i < 8; ++i) acc[i] = 0.f;
  for (int k = 0; k < 256; ++k){
    float ev = er[k];
    const f32x4* wr = (const f32x4*)(memW + k * 256 + slot * 32);
    #pragma unroll
    for (int i = 0; i < 8; ++i) acc[i] += ev * wr[i];
  }
  unsigned short* pmB = (unsigned short*)(ws + OFF_PMB);
  unsigned short* dst = pmB + ((size_t)(b * 512 + trow)) * 256 + slot * 32;
  #pragma unroll
  for (int i = 0; i < 8; ++i){
    u32x2 pk;
    pk[0] = (unsigned)f2bf(acc[i][0]) | ((unsigned)f2bf(acc[i][1]) << 16);
    pk[1] = (unsigned)f2bf(acc[i][2]) | ((unsigned)f2bf(acc[i][3]) << 16);
    *(u32x2*)(dst + i * 4) = pk;
  }
  const float* e2 = enc + ((size_t)(b * 512 + th * 64)) * 256;
  unsigned* eb = (unsigned*)((unsigned short*)(ws + OFF_ENCB) + ((size_t)(b * 512 + th * 64)) * 256);
  for (int i = tid; i < 64 * 128; i += NTH){
    float v0 = e2[i * 2], v1 = e2[i * 2 + 1];
    eb[i] = (unsigned)f2bf(v0) | ((unsigned)f2bf(v1) << 16);
  }
}

// ---------------- persistent recurrent decoder ----------------
// 4 independent groups of 64 WGs (group g owns batches 16g..16g+15).
// 3 group-local barriers/step. pm/enc slices staged in registers once.
// q via in-wave K-split (shfl_xor 32). P4/P5 gathers issued early at P2 head
// (attH[w], h1a[rb], h2a[rb] are barrier-stable there) -> load latency off
// the serial path.
__global__ __launch_bounds__(NTH, 2) void decoder_k(
    float* __restrict__ ws, float* __restrict__ out,
    const int* __restrict__ memlen,
    const float* __restrict__ vW,
    const float* __restrict__ attBi, const float* __restrict__ attBh,
    const float* __restrict__ projB,
    const float* __restrict__ d1Bh,
    const float* __restrict__ d2Bi, const float* __restrict__ d2Bh)
{
  const int wg = blockIdx.x, tid = threadIdx.x;
  int* bar = (int*)ws;
  float* attH = ws + OFF_ATTH;       // [2][64][256]
  float* h1a  = ws + OFF_H1;
  float* h2a  = ws + OFF_H2;
  float* const curB[2]  = { ws + OFF_CURP, ws + OFF_Q };    // ctx partial-sum buffers
  float* const attSB[2] = { ws + OFF_ATTS, ws + OFF_ATTS + 64 };
  float* d1v  = ws + OFF_D1;
  const float* C1v = ws + OFF_C1;
  const unsigned short* preB16 = (const unsigned short*)(ws + OFF_PRE);
  const unsigned short* pmB  = (const unsigned short*)(ws + OFF_PMB);
  const unsigned short* encB = (const unsigned short*)(ws + OFF_ENCB);
  const unsigned short* qtb = (const unsigned short*)(out + GOFF);
  float* d2a  = ws + OFF_D2A;

  __shared__ float BUF[12416];
  __shared__ float qL[256], vL[256];
  __shared__ float eL[128];
  __shared__ float ewGi[192], ewGh[192], pdec[128];

  if (tid < 256) vL[tid] = vW[tid];

  // group decomposition: g owns batches [g*16, g*16+16)
  const int g = wg >> 6, l = wg & 63;
  const int sl = l;                       // GRU slice 0..63 (j = sl*4..+4)
  const int b0 = g << 4;                  // batch base for GRU phases
  const int b2 = b0 + (l >> 2), ch2 = l & 3;   // attention batch / enc chunk
  const int len2 = memlen[b2];
  const unsigned short* blob = (const unsigned short*)(ws + OFF_BLOB) + (size_t)sl * BLOB_STR;

  const int bq = tid & 15, x = tid >> 4;
  const int cs = (x >= 12) ? (x - 12) : x;
  const int gg = cs % 3, jh = cs / 3;
  const int col = gg * 256 + sl * 4 + jh;

  const int r0 = tid >> 6, c0 = (tid & 63) << 2;   // gather mapping (rows 0..7 / 8..15)
  const int r1 = r0 + 8;
  const int prr = tid >> 4, pcc = (tid & 15) * 8;  // prenet unpack mapping (tid<256)

  // ---- persistent register staging of this thread's pm/enc slices ----
  u32x4 pmv[8], env[8];
  {
    int te = tid >> 2, part = tid & 3;
    const u32x4* pmp = (const u32x4*)(pmB + ((size_t)(b2*512 + ch2*128 + te))*256 + part*64);
    #pragma unroll
    for (int i = 0; i < 8; ++i) pmv[i] = pmp[i];
    int ich = tid >> 5, dblk = tid & 31;
    const unsigned short* ep = encB + ((size_t)(b2*512 + ch2*128 + ich*8))*256 + dblk*8;
    #pragma unroll
    for (int i = 0; i < 8; ++i) env[i] = *(const u32x4*)(ep + i*256);
  }

  // ---- initial prefetch of P0 inputs for t=0 (rb=1 buffers; all zeroed) ----
  f32x4 pH0, pH1, pC0, pC1;
  float pS0, pS1;
  u32x4 ppre = 0u;
  {
    const float* gHn = attH + 16384 + b0*256;
    const float* gCn = curB[1] + b0*256;
    pH0 = cload16(gHn + (r0<<8) + c0); pH1 = cload16(gHn + (r1<<8) + c0);
    pC0 = cload16(gCn + (r0<<8) + c0); pC1 = cload16(gCn + (r1<<8) + c0);
    pS0 = aload4(attSB[1] + b0 + r0);  pS1 = aload4(attSB[1] + b0 + r1);
    if (tid < 256) ppre = cload16u(preB16 + (b0 + prr)*128 + pcc);
  }

  int bn = 0;
  for (int t = 0; t < TDEC; ++t){
    const int w = t & 1, rb = w ^ 1;
    f32x4 eA0, eA1, eH0, eH1, eG0, eG1;   // early-issued P4/P5 gathers

    // ===== P0: attention GRU: h' = GRU(cat(pre, ctx_{t-1}), att_h) =====
    {
      float* xL = BUF;              // [16][388]: [0:128)=pre, [128:384)=ctx
      float* hL = BUF + 6208;       // [16][260]: att_h prev
      asm volatile("s_waitcnt vmcnt(0)" : "+v"(pH0),"+v"(pH1),"+v"(pC0),"+v"(pC1),"+v"(ppre));
      float iv0 = pS0 > 0.f ? 1.f/pS0 : 0.f, iv1 = pS1 > 0.f ? 1.f/pS1 : 0.f;
      if (tid < 256){
        float* xd = xL + prr*388 + pcc;
        xd[0]=blo(ppre[0]); xd[1]=bhi(ppre[0]); xd[2]=blo(ppre[1]); xd[3]=bhi(ppre[1]);
        xd[4]=blo(ppre[2]); xd[5]=bhi(ppre[2]); xd[6]=blo(ppre[3]); xd[7]=bhi(ppre[3]);
      }
      *(f32x4*)(hL + r0*260 + c0) = pH0; *(f32x4*)(hL + r1*260 + c0) = pH1;
      *(f32x4*)(xL + r0*388 + 128 + c0) = pC0*iv0; *(f32x4*)(xL + r1*388 + 128 + c0) = pC1*iv1;
      // zero this step's ctx/attS accumulators (buffer w; last read 2 steps ago)
      if (tid < 64) astore4(curB[w] + wg*64 + tid, 0.f);
      if (sl == 0 && tid < 16) astore4(attSB[w] + b0 + tid, 0.f);
      ldsbar();
      if (x < 12)
        ewGi[cs*16 + bq] = bdot<48>(blob + BO_AI + cs*384, xL + bq*388) + attBi[col];
      else if (x < 24)
        ewGh[cs*16 + bq] = bdot<32>(blob + BO_AH + cs*256, hL + bq*260) + attBh[col];
      ldsbar();
      if (tid < 64){
        int bt = tid & 15, jj = tid >> 4;
        int j = sl*4 + jj;
        float ir = ewGi[(jj*3+0)*16+bt] + ewGh[(jj*3+0)*16+bt];
        float iz = ewGi[(jj*3+1)*16+bt] + ewGh[(jj*3+1)*16+bt];
        float inn = ewGi[(jj*3+2)*16+bt];
        float hn  = ewGh[(jj*3+2)*16+bt];
        float rg = fsig(ir), z = fsig(iz);
        float n = ftanh(inn + rg * hn);
        float h = hL[bt*260 + j];
        astore4(attH + w*16384 + (b0+bt)*256 + j, (1.f - z)*n + z*h);
      }
    }
    gbar(bar, g, l, ++bn);

    // ===== P2: q (in-wave K-split) + scoring + exp + partial sum/context =====
    {
      float* ctxP = BUF;            // [4096]
      float* qIn  = BUF + 8192;     // [256] att_h' row for this WG's batch
      // early-issue P4/P5 gathers (attH[w], h1a[rb], h2a[rb] stable since gbar#1)
      eA0 = cload16(attH + w*16384 + ((b0+r0)<<8) + c0);
      eA1 = cload16(attH + w*16384 + ((b0+r1)<<8) + c0);
      eH0 = cload16(h1a + rb*16384 + ((b0+r0)<<8) + c0);
      eH1 = cload16(h1a + rb*16384 + ((b0+r1)<<8) + c0);
      eG0 = cload16(h2a + rb*16384 + ((b0+r0)<<8) + c0);
      eG1 = cload16(h2a + rb*16384 + ((b0+r1)<<8) + c0);
      if (tid < 64){
        f32x4 v = cload16w(attH + w*16384 + b2*256 + tid*4);
        *(f32x4*)(qIn + tid*4) = v;
      }
      ldsbar();
      {
        // q[j] = att_h' . qW[:,j]; lane pairs (lane, lane^32) split K halves
        int lane = tid & 63;
        int j = (tid >> 6)*32 + (lane & 31), hf = lane >> 5;
        const unsigned short* qw = qtb + j*8 + (size_t)hf*32768;
        const float* qx = qIn + hf*128;
        f32x4 aA = 0.f, aB = 0.f;
        #pragma unroll 4
        for (int it = 0; it < 16; ++it){
          u32x4 u = *(const u32x4*)(qw + (size_t)it*2048);
          f32x4 a = *(const f32x4*)(qx + it*8);
          f32x4 b = *(const f32x4*)(qx + it*8 + 4);
          f32x4 w0, w1;
          w0[0]=blo(u[0]); w0[1]=bhi(u[0]); w0[2]=blo(u[1]); w0[3]=bhi(u[1]);
          w1[0]=blo(u[2]); w1[1]=bhi(u[2]); w1[2]=blo(u[3]); w1[3]=bhi(u[3]);
          aA += w0*a; aB += w1*b;
        }
        f32x4 s4 = aA + aB;
        float s = s4[0]+s4[1]+s4[2]+s4[3];
        s += __shfl_xor(s, 32);
        if (hf == 0) qL[j] = s;
      }
      ldsbar();
      {
        int te = tid >> 2, part = tid & 3;
        int ge = ch2*128 + te;
        float a4 = 0.f;
        #pragma unroll
        for (int i = 0; i < 8; ++i){
          u32x4 u = pmv[i];
          int kb = part*64 + i*8;
          a4 += ftanh(blo(u[0]) + qL[kb+0]) * vL[kb+0];
          a4 += ftanh(bhi(u[0]) + qL[kb+1]) * vL[kb+1];
          a4 += ftanh(blo(u[1]) + qL[kb+2]) * vL[kb+2];
          a4 += ftanh(bhi(u[1]) + qL[kb+3]) * vL[kb+3];
          a4 += ftanh(blo(u[2]) + qL[kb+4]) * vL[kb+4];
          a4 += ftanh(bhi(u[2]) + qL[kb+5]) * vL[kb+5];
          a4 += ftanh(blo(u[3]) + qL[kb+6]) * vL[kb+6];
          a4 += ftanh(bhi(u[3]) + qL[kb+7]) * vL[kb+7];
        }
        a4 += __shfl_xor(a4, 1);
        a4 += __shfl_xor(a4, 2);
        float e = (ge < len2) ? __expf(a4) : 0.f;
        if (part == 0){
          eL[te] = e;
          out[AOFF + ((size_t)(b2*TDEC + t))*512 + ge] = e;
        }
      }
      ldsbar();
      if (tid < 64){
        float s = eL[tid] + eL[tid + 64];
        #pragma unroll
        for (int o = 32; o > 0; o >>= 1) s += __shfl_down(s, o);
        if (tid == 0) aadd(attSB[w] + b2, s);
      }
      {
        int ich = tid >> 5, dblk = tid & 31;
        f32x4 acA = 0.f, acB = 0.f;
        #pragma unroll
        for (int i = 0; i < 8; ++i){
          u32x4 u = env[i];
          float e = eL[ich*8 + i];
          acA[0] += e*blo(u[0]); acA[1] += e*bhi(u[0]);
          acA[2] += e*blo(u[1]); acA[3] += e*bhi(u[1]);
          acB[0] += e*blo(u[2]); acB[1] += e*bhi(u[2]);
          acB[2] += e*blo(u[3]); acB[3] += e*bhi(u[3]);
        }
        *(f32x4*)(ctxP + tid*8) = acA;
        *(f32x4*)(ctxP + tid*8 + 4) = acB;
      }
      ldsbar();
      if (tid < 256){
        int dblk = tid >> 3, d = tid & 7;
        float s = 0.f;
        #pragma unroll
        for (int i = 0; i < 16; ++i) s += ctxP[i*256 + dblk*8 + d];
        aadd(curB[w] + b2*256 + dblk*8 + d, s);
      }
    }
    gbar(bar, g, l, ++bn);

    // ===== P4: GRU1 via fused M1 + decin side-dot; d1 = h1' + decin =====
    {
      float* yL  = BUF;             // [16][516]: [0:256)=att_h', [256:512)=ctxN
      float* h1L = BUF + 8256;      // [16][260]
      const float* gC = curB[w] + b0*256;
      f32x4 vC0 = cload16(gC + (r0<<8) + c0), vC1 = cload16(gC + (r1<<8) + c0);
      float s0 = aload4(attSB[w] + b0 + r0), s1 = aload4(attSB[w] + b0 + r1);
      asm volatile("s_waitcnt vmcnt(0)" : "+v"(eA0),"+v"(eA1),"+v"(eH0),"+v"(eH1),"+v"(vC0),"+v"(vC1));
      float iv0 = s0 > 0.f ? 1.f/s0 : 0.f, iv1 = s1 > 0.f ? 1.f/s1 : 0.f;
      *(f32x4*)(yL + r0*516 + c0) = eA0;       *(f32x4*)(yL + r1*516 + c0) = eA1;
      *(f32x4*)(h1L + r0*260 + c0) = eH0;      *(f32x4*)(h1L + r1*260 + c0) = eH1;
      *(f32x4*)(yL + r0*516 + 256 + c0) = vC0*iv0; *(f32x4*)(yL + r1*516 + 256 + c0) = vC1*iv1;
      ldsbar();
      if (x < 12)
        ewGi[cs*16 + bq] = bdot<64>(blob + BO_M1 + cs*512, yL + bq*516) + C1v[col];
      else if (x < 24)
        ewGh[cs*16 + bq] = bdot<32>(blob + BO_H1 + cs*256, h1L + bq*260) + d1Bh[col];
      else {
        int idx = tid - 384;
        int bq2 = idx & 15, cc = (idx >> 4) & 3, half = idx >> 6;
        pdec[idx] = bdot<32>(blob + BO_PJ + cc*512 + half*256, yL + bq2*516 + half*256);
      }
      ldsbar();
      if (tid < 64){
        int bt = tid & 15, jj = tid >> 4;
        int j = sl*4 + jj;
        float ir = ewGi[(jj*3+0)*16+bt] + ewGh[(jj*3+0)*16+bt];
        float iz = ewGi[(jj*3+1)*16+bt] + ewGh[(jj*3+1)*16+bt];
        float inn = ewGi[(jj*3+2)*16+bt];
        float hn  = ewGh[(jj*3+2)*16+bt];
        float rg = fsig(ir), z = fsig(iz);
        float n = ftanh(inn + rg * hn);
        float hv = h1L[bt*260 + j];
        float hnew = (1.f - z)*n + z*hv;
        float dec = pdec[jj*16 + bt] + pdec[64 + jj*16 + bt] + projB[j];
        astore4(h1a + w*16384 + (b0+bt)*256 + j, hnew);
        astore4(d1v + (b0+bt)*256 + j, hnew + dec);
      }
      if (sl == 0 && tid < 16)
        ws[OFF_SUMS + t*64 + b0 + tid] = aload4(attSB[w] + b0 + tid);
    }
    gbar(bar, g, l, ++bn);

    // ===== P5: GRU2; d2 = h2' + d1 (feeds outputs only; no group barrier).
    //        Also prefetch next-step P0 inputs (barrier-stable by now). =====
    {
      float* dL  = BUF;             // [16][260]
      float* h2L = BUF + 4160;      // [16][260]
      const float* gD = d1v + b0*256;
      f32x4 vD0 = cload16(gD + (r0<<8) + c0), vD1 = cload16(gD + (r1<<8) + c0);
      asm volatile("s_waitcnt vmcnt(0)" : "+v"(vD0),"+v"(vD1),"+v"(eG0),"+v"(eG1));
      {
        // prefetch for P0(t+1): rb(t+1)==w(t) buffers, pre row t+1
        const float* gHn = attH + w*16384 + b0*256;
        const float* gCn = curB[w] + b0*256;
        pH0 = cload16(gHn + (r0<<8) + c0); pH1 = cload16(gHn + (r1<<8) + c0);
        pC0 = cload16(gCn + (r0<<8) + c0); pC1 = cload16(gCn + (r1<<8) + c0);
        pS0 = aload4(attSB[w] + b0 + r0);  pS1 = aload4(attSB[w] + b0 + r1);
        int tn = (t + 1 < TDEC) ? (t + 1) : 0;
        if (tid < 256) ppre = cload16u(preB16 + (size_t)tn*8192 + (b0 + prr)*128 + pcc);
      }
      *(f32x4*)(dL + r0*260 + c0) = vD0;  *(f32x4*)(dL + r1*260 + c0) = vD1;
      *(f32x4*)(h2L + r0*260 + c0) = eG0; *(f32x4*)(h2L + r1*260 + c0) = eG1;
      ldsbar();
      if (x < 12)
        ewGi[cs*16 + bq] = bdot<32>(blob + BO_I2 + cs*256, dL + bq*260) + d2Bi[col];
      else if (x < 24)
        ewGh[cs*16 + bq] = bdot<32>(blob + BO_H2 + cs*256, h2L + bq*260) + d2Bh[col];
      ldsbar();
      if (tid < 64){
        int bt = tid & 15, jj = tid >> 4;
        int j = sl*4 + jj;
        float ir = ewGi[(jj*3+0)*16+bt] + ewGh[(jj*3+0)*16+bt];
        float iz = ewGi[(jj*3+1)*16+bt] + ewGh[(jj*3+1)*16+bt];
        float inn = ewGi[(jj*3+2)*16+bt];
        float hn  = ewGh[(jj*3+2)*16+bt];
        float rg = fsig(ir), z = fsig(iz);
        float n = ftanh(inn + rg * hn);
        float hv = h2L[bt*260 + j];
        float hnew = (1.f - z)*n + z*hv;
        astore4(h2a + w*16384 + (b0+bt)*256 + j, hnew);
        d2a[t*16384 + j*64 + (b0+bt)] = hnew + dL[bt*260 + j];
      }
      ldsbar();  // protect BUF/ew from next-iteration P0 (LDS only; vm stays in flight)
    }
  }
}

// ---------------- alignment rescale ----------------
__global__ __launch_bounds__(NTH, 1) void rescale_k(const float* __restrict__ ws,
                                                    float* __restrict__ out){
  int blk = blockIdx.x;
  int b = blk / TDEC, t = blk - b * TDEC;
  float s = ws[OFF_SUMS + t*64 + b];
  float inv = (s > 0.f) ? 1.f/s : 0.f;
  out[AOFF + (size_t)blk*512 + threadIdx.x] *= inv;
}

// ---------------- deferred mel/gate heads ----------------
__global__ __launch_bounds__(NTH, 1) void outproj_k(const float* __restrict__ ws,
    float* __restrict__ out, const float* __restrict__ melW, const float* __restrict__ melB,
    const float* __restrict__ gateW, const float* __restrict__ gateB){
  int t = blockIdx.x, tid = threadIdx.x;
  int cx = tid & 255, bh = tid >> 8;
  const float* src = ws + OFF_D2A + t*16384 + bh*32;
  float acc[32];
  #pragma unroll
  for (int i = 0; i < 32; ++i) acc[i] = 0.f;
  bool ismel = (cx < 160);
  bool isgate = (cx >= 160 && cx < 162);
  for (int j = 0; j < 256; ++j){
    float wv = 0.f;
    if (ismel) wv = melW[j*160 + cx];
    else if (isgate) wv = gateW[j*2 + (cx - 160)];
    const f32x4* dp = (const f32x4*)(src + j*64);
    f32x4 vv[8];
    #pragma unroll
    for (int q = 0; q < 8; ++q) vv[q] = dp[q];
    #pragma unroll
    for (int q = 0; q < 8; ++q){
      acc[q*4+0] += vv[q][0]*wv; acc[q*4+1] += vv[q][1]*wv;
      acc[q*4+2] += vv[q][2]*wv; acc[q*4+3] += vv[q][3]*wv;
    }
  }
  if (ismel){
    float bb = melB[cx];
    #pragma unroll
    for (int i = 0; i < 32; ++i){
      int b = bh*32 + i;
      out[((size_t)(b*TDEC + t))*160 + cx] = acc[i] + bb;
    }
  } else if (isgate){
    int g = cx - 160;
    float bb = gateB[g];
    #pragma unroll
    for (int i = 0; i < 32; ++i){
      int b = bh*32 + i;
      out[GOFF + ((size_t)(b*TDEC + t))*2 + g] = fsig(acc[i] + bb);
    }
  }
}

extern "C" void kernel_launch(void* const* d_in, const int* in_sizes, int n_in,
                              void* d_out, int out_size, void* d_ws, size_t ws_size,
                              hipStream_t stream)
{
  (void)in_sizes; (void)n_in; (void)out_size; (void)ws_size;
  const float* enc   = (const float*)d_in[0];
  const float* inp   = (const float*)d_in[1];
  const int*   mlen  = (const int*)d_in[2];
  const float* preW1 = (const float*)d_in[3];
  const float* preB1 = (const float*)d_in[4];
  const float* preW2 = (const float*)d_in[5];
  const float* preB2 = (const float*)d_in[6];
  const float* memW  = (const float*)d_in[7];
  const float* qW    = (const float*)d_in[8];
  const float* vW    = (const float*)d_in[9];
  const float* attWi = (const float*)d_in[10];
  const float* attWh = (const float*)d_in[11];
  const float* attBi = (const float*)d_in[12];
  const float* attBh = (const float*)d_in[13];
  const float* projW = (const float*)d_in[14];
  const float* projB = (const float*)d_in[15];
  const float* d1Wi  = (const float*)d_in[16];
  const float* d1Wh  = (const float*)d_in[17];
  const float* d1Bi  = (const float*)d_in[18];
  const float* d1Bh  = (const float*)d_in[19];
  const float* d2Wi  = (const float*)d_in[20];
  const float* d2Wh  = (const float*)d_in[21];
  const float* d2Bi  = (const float*)d_in[22];
  const float* d2Bh  = (const float*)d_in[23];
  const float* melW  = (const float*)d_in[24];
  const float* melB  = (const float*)d_in[25];
  const float* gateW = (const float*)d_in[26];
  const float* gateB = (const float*)d_in[27];
  float* ws = (float*)d_ws;
  float* out = (float*)d_out;

  hipMemsetAsync(d_ws, 0, (size_t)ZERO_FLOATS * sizeof(float), stream);

  dim3 tt(256);
  transpose_k<<<dim3(24, 12), tt, 0, stream>>>(attWi, ws + T_WIT_A, 384, 768);
  transpose_k<<<dim3(24, 8),  tt, 0, stream>>>(attWh, ws + T_WHT_A, 256, 768);
  transpose_k<<<dim3(24, 8),  tt, 0, stream>>>(d1Wh,  ws + T_WHT1, 256, 768);
  transpose_k<<<dim3(24, 8),  tt, 0, stream>>>(d2Wi,  ws + T_WIT2, 256, 768);
  transpose_k<<<dim3(24, 8),  tt, 0, stream>>>(d2Wh,  ws + T_WHT2, 256, 768);
  transpose_k<<<dim3(8, 16),  tt, 0, stream>>>(projW, ws + T_PJT, 512, 256);
  transpose_k<<<dim3(8, 8),   tt, 0, stream>>>(qW,    ws + T_QWT, 256, 256);
  fuse_k<<<3072, 128, 0, stream>>>(projW, d1Wi, ws + T_M1);
  c1_k<<<3, 256, 0, stream>>>(projB, d1Wi, d1Bi, ws + OFF_C1);
  transpose_k<<<dim3(24, 16), tt, 0, stream>>>(ws + T_M1, ws + T_M1T, 512, 768);
  pack_k<<<64, NTH, 0, stream>>>(ws);
  qt_k<<<256, 256, 0, stream>>>(ws, out);

  prenet_k<<<dim3(TDEC, 2), NTH, 0, stream>>>(ws, inp, preW1, preB1, preW2, preB2);
  pm_k<<<512, NTH, 0, stream>>>(ws, enc, memW);
  decoder_k<<<NWG, NTH, 0, stream>>>(ws, out, mlen, vW, attBi, attBh, projB,
                                     d1Bh, d2Bi, d2Bh);
  rescale_k<<<64 * TDEC, NTH, 0, stream>>>(ws, out);
  outproj_k<<<TDEC, NTH, 0, stream>>>(ws, out, melW, melB, gateW, gateB);
}

// Round 6
// 12015.826 us; speedup vs baseline: 1.4364x; 1.0994x over previous
//
#include <hip/hip_runtime.h>

#define TDEC 400
#define NTH 512
#define NWG 256

typedef float f32x4 __attribute__((ext_vector_type(4)));
typedef unsigned u32x4 __attribute__((ext_vector_type(4)));
typedef unsigned u32x2 __attribute__((ext_vector_type(2)));

// ---------------- ws layout (float offsets) ----------------
#define OFF_BAR   0
#define OFF_ATTH  11264
#define OFF_H1    44032
#define OFF_H2    76800
#define OFF_CURP  109568       /* ctx buffer parity 0 [64][256] */
#define OFF_ATTS  125952       /* attS [2][64] */
#define OFF_Q     126208       /* ctx buffer parity 1 [64][256] */
#define ZERO_FLOATS 142592     /* memset covers BAR..Q inclusive */
#define OFF_D1    142592
#define OFF_SUMS  158976
#define OFF_C1    184576
#define OFF_PRE   185600       /* bf16 [400][64][128] */
#define OFF_PMB   1824000      /* bf16 [64][512][256] */
#define OFF_ENCB  6018304      /* bf16 [64][512][256] */
#define OFF_D2A   10212608     /* fp32 [400][256][64]; setup overlays below */
#define T_WIT_A   10212608
#define T_WHT_A   10507520
#define T_M1T     10704128
#define T_WHT1    11097344
#define T_PJT     11293952
#define T_WIT2    11425024
#define T_WHT2    11621632
#define T_QWT     11818240
#define T_M1      11883776
#define OFF_BLOB  16766208     /* bf16: 64 slices x BLOB_STR */
// total 17,618,176 floats = 70.5 MB

#define BLOB_N   26112
#define BLOB_STR 26624
// blob section offsets (ushort units)
#define BO_AI  0
#define BO_AH  4608
#define BO_Q   7680
#define BO_M1  8704
#define BO_H1  14848
#define BO_PJ  17920
#define BO_I2  19968
#define BO_H2  23040

#define AOFF 4096000
#define GOFF 17203200          /* gates region; doubles as QT scratch during decoder */

// group-local barrier counter slots (int offsets); group g adds +g*64
#define MSTI  (8*1024)
#define GENI  (9*1024)
#define FAILI (10*1024)

__device__ __forceinline__ float fsig(float x){ return 1.0f/(1.0f+__expf(-x)); }
__device__ __forceinline__ float ftanh(float x){ float e = __expf(2.0f*x); return 1.0f - 2.0f/(e+1.0f); }
__device__ __forceinline__ float blo(unsigned u){ return __uint_as_float(u<<16); }
__device__ __forceinline__ float bhi(unsigned u){ return __uint_as_float(u & 0xffff0000u); }

__device__ __forceinline__ f32x4 cload16(const float* p){
  f32x4 r;
  asm volatile("global_load_dwordx4 %0, %1, off sc0 sc1" : "=v"(r) : "v"(p));
  return r;
}
__device__ __forceinline__ u32x4 cload16u(const unsigned short* p){
  u32x4 r;
  asm volatile("global_load_dwordx4 %0, %1, off sc0 sc1" : "=v"(r) : "v"(p));
  return r;
}
__device__ __forceinline__ float aload4(const float* p){
  unsigned u = __hip_atomic_load((const unsigned*)p, __ATOMIC_RELAXED, __HIP_MEMORY_SCOPE_AGENT);
  return __uint_as_float(u);
}
__device__ __forceinline__ void astore4(float* p, float v){
  __hip_atomic_store((unsigned*)p, __float_as_uint(v), __ATOMIC_RELAXED, __HIP_MEMORY_SCOPE_AGENT);
}
__device__ __forceinline__ void aadd(float* p, float v){
  __hip_atomic_fetch_add(p, v, __ATOMIC_RELAXED, __HIP_MEMORY_SCOPE_AGENT);
}
__device__ __forceinline__ int aloadi(const int* p){
  return __hip_atomic_load(p, __ATOMIC_RELAXED, __HIP_MEMORY_SCOPE_AGENT);
}

// LDS-only barrier: does NOT drain vmcnt.
__device__ __forceinline__ void ldsbar(){
  __builtin_amdgcn_sched_barrier(0);
  asm volatile("s_waitcnt lgkmcnt(0)" ::: "memory");
  __builtin_amdgcn_s_barrier();
  __builtin_amdgcn_sched_barrier(0);
}

// group-local (64-WG) fence-free barrier: monotonic counters, relaxed agent
// atomics. 8 arrival counters x 8 arrivals per round, per group.
__device__ __forceinline__ void gbar(int* bar, int g, int l, int n){
  asm volatile("s_waitcnt vmcnt(0)" ::: "memory");
  __syncthreads();
  if (threadIdx.x == 0){
    if (aloadi(&bar[FAILI]) == 0){
      int a = __hip_atomic_fetch_add(&bar[(l&7)*1024 + g*64], 1, __ATOMIC_RELAXED, __HIP_MEMORY_SCOPE_AGENT);
      if (a == 8*n - 1){
        int m = __hip_atomic_fetch_add(&bar[MSTI + g*64], 1, __ATOMIC_RELAXED, __HIP_MEMORY_SCOPE_AGENT);
        if (m == 8*n - 1)
          __hip_atomic_store(&bar[GENI + g*64], n, __ATOMIC_RELAXED, __HIP_MEMORY_SCOPE_AGENT);
      }
      int sp = 0;
      while (aloadi(&bar[GENI + g*64]) < n){
        __builtin_amdgcn_s_sleep(1);
        if (++sp > (1<<20)){
          __hip_atomic_store(&bar[FAILI], 1, __ATOMIC_RELAXED, __HIP_MEMORY_SCOPE_AGENT);
          break;
        }
      }
    }
  }
  __syncthreads();
}

__device__ __forceinline__ unsigned short f2bf(float f){
  unsigned u = __float_as_uint(f);
  return (unsigned short)((u + 0x7fffu + ((u>>16)&1u)) >> 16);
}

// bf16-weight dot with dual f32x4 accumulators (8x ILP vs scalar acc chain)
template<int N8>
__device__ __forceinline__ float bdot(const unsigned short* wr, const float* xr){
  f32x4 accA = 0.f, accB = 0.f;
  #pragma unroll 4
  for (int k = 0; k < N8; ++k){
    u32x4 u = *(const u32x4*)(wr + k*8);
    f32x4 a = *(const f32x4*)(xr + k*8);
    f32x4 b = *(const f32x4*)(xr + k*8 + 4);
    f32x4 w0, w1;
    w0[0]=blo(u[0]); w0[1]=bhi(u[0]); w0[2]=blo(u[1]); w0[3]=bhi(u[1]);
    w1[0]=blo(u[2]); w1[1]=bhi(u[2]); w1[2]=blo(u[3]); w1[3]=bhi(u[3]);
    accA += w0*a; accB += w1*b;
  }
  f32x4 s = accA + accB;
  return s[0]+s[1]+s[2]+s[3];
}

// ---------------- generic 32x32 tiled transpose ----------------
__global__ __launch_bounds__(256, 1) void transpose_k(const float* __restrict__ in,
                                                      float* __restrict__ outp, int K, int C){
  __shared__ float tl[32][33];
  int c0 = blockIdx.x * 32, k0 = blockIdx.y * 32;
  int tx = threadIdx.x & 31, ty = threadIdx.x >> 5;
  for (int i = ty; i < 32; i += 8){
    int k = k0 + i, c = c0 + tx;
    if (k < K && c < C) tl[i][tx] = in[k * C + c];
  }
  __syncthreads();
  for (int i = ty; i < 32; i += 8){
    int c = c0 + i, k = k0 + tx;
    if (c < C && k < K) outp[c * K + k] = tl[tx][i];
  }
}

// ---------------- M1 = projW @ d1Wi  (512x768) ----------------
__global__ __launch_bounds__(128, 1) void fuse_k(const float* __restrict__ projW,
    const float* __restrict__ d1Wi, float* __restrict__ M1){
  int jt = blockIdx.x % 6, i = blockIdx.x / 6;
  int j = jt * 128 + threadIdx.x;
  float acc = 0.f;
  for (int k = 0; k < 256; ++k) acc += projW[i*256+k] * d1Wi[k*768+j];
  M1[i*768+j] = acc;
}

// ---------------- c1 = projB @ d1Wi + d1Bi ----------------
__global__ __launch_bounds__(256, 1) void c1_k(const float* __restrict__ projB,
    const float* __restrict__ d1Wi, const float* __restrict__ d1Bi, float* __restrict__ C1){
  int j = blockIdx.x * 256 + threadIdx.x;
  float acc = d1Bi[j];
  for (int k = 0; k < 256; ++k) acc += projB[k] * d1Wi[k*768+j];
  C1[j] = acc;
}

// ---------------- pack per-sl bf16 weight blobs ----------------
__global__ __launch_bounds__(512, 1) void pack_k(float* __restrict__ ws){
  int sl = blockIdx.x;
  const float* TAI = ws + T_WIT_A;
  const float* TAH = ws + T_WHT_A;
  const float* TM1 = ws + T_M1T;
  const float* TH1 = ws + T_WHT1;
  const float* TPJ = ws + T_PJT;
  const float* TI2 = ws + T_WIT2;
  const float* TH2 = ws + T_WHT2;
  const float* TQ  = ws + T_QWT;
  unsigned short* blob = (unsigned short*)(ws + OFF_BLOB) + (size_t)sl * BLOB_STR;
  for (int idx = threadIdx.x; idx < BLOB_N; idx += 512){
    float v; int cs, k, o;
    if (idx < BO_AH){ cs = idx / 384; k = idx - cs*384;
      v = TAI[((cs%3)*256 + sl*4 + cs/3)*384 + k]; }
    else if (idx < BO_Q){ o = idx - BO_AH; cs = o >> 8; k = o & 255;
      v = TAH[((cs%3)*256 + sl*4 + cs/3)*256 + k]; }
    else if (idx < BO_M1){ o = idx - BO_Q; cs = o >> 8; k = o & 255;
      v = TQ[(sl*4 + cs)*256 + k]; }
    else if (idx < BO_H1){ o = idx - BO_M1; cs = o >> 9; k = o & 511;
      v = TM1[((cs%3)*256 + sl*4 + cs/3)*512 + k]; }
    else if (idx < BO_PJ){ o = idx - BO_H1; cs = o >> 8; k = o & 255;
      v = TH1[((cs%3)*256 + sl*4 + cs/3)*256 + k]; }
    else if (idx < BO_I2){ o = idx - BO_PJ; cs = o >> 9; k = o & 511;
      v = TPJ[(sl*4 + cs)*512 + k]; }
    else if (idx < BO_H2){ o = idx - BO_I2; cs = o >> 8; k = o & 255;
      v = TI2[((cs%3)*256 + sl*4 + cs/3)*256 + k]; }
    else { o = idx - BO_H2; cs = o >> 8; k = o & 255;
      v = TH2[((cs%3)*256 + sl*4 + cs/3)*256 + k]; }
    blob[idx] = f2bf(v);
  }
}

// ---------------- QT: coalesced bf16 qW^T copy into out's gate region ----------------
__global__ __launch_bounds__(256, 1) void qt_k(const float* __restrict__ ws,
                                               float* __restrict__ out){
  unsigned short* qtb = (unsigned short*)(out + GOFF);
  const float* TQ = ws + T_QWT;
  int idx = blockIdx.x * 256 + threadIdx.x;   // 65536 total
  int it = idx >> 11, j = (idx >> 3) & 255, e = idx & 7;
  qtb[idx] = f2bf(TQ[j*256 + it*8 + e]);
}

// ---------------- prenet: bf16 output ----------------
__global__ __launch_bounds__(NTH, 1) void prenet_k(float* __restrict__ ws,
    const float* __restrict__ inp, const float* __restrict__ W1, const float* __restrict__ B1,
    const float* __restrict__ W2, const float* __restrict__ B2){
  __shared__ float xT[160 * 33];
  __shared__ float hT[256 * 33];
  int t = blockIdx.x, half = blockIdx.y, tid = threadIdx.x;
  int bbase = half * 32;
  for (int r = tid; r < 32 * 160; r += NTH){
    int b2 = r / 160; int k = r - b2 * 160;
    xT[k * 33 + b2] = (t == 0) ? 0.f : inp[((bbase + b2) * TDEC + (t - 1)) * 160 + k];
  }
  __syncthreads();
  int bl = tid & 31, slot = tid >> 5;
  float acc1[16];
  #pragma unroll
  for (int i = 0; i < 16; ++i) acc1[i] = 0.f;
  for (int k = 0; k < 160; ++k){
    float xv = xT[k * 33 + bl];
    const float* wr = W1 + k * 256 + slot * 16;
    #pragma unroll
    for (int i = 0; i < 16; ++i) acc1[i] += xv * wr[i];
  }
  #pragma unroll
  for (int i = 0; i < 16; ++i){
    int c = slot * 16 + i;
    hT[c * 33 + bl] = fmaxf(acc1[i] + B1[c], 0.f);
  }
  __syncthreads();
  float acc2[8];
  #pragma unroll
  for (int i = 0; i < 8; ++i) acc2[i] = 0.f;
  for (int k = 0; k < 256; ++k){
    float hv = hT[k * 33 + bl];
    const float* wr = W2 + k * 128 + slot * 8;
    #pragma unroll
    for (int i = 0; i < 8; ++i) acc2[i] += hv * wr[i];
  }
  unsigned short* dst = (unsigned short*)(ws + OFF_PRE) + (size_t)t*8192 + (bbase + bl)*128 + slot*8;
  u32x4 pk;
  #pragma unroll
  for (int i = 0; i < 4; ++i){
    float v0 = fmaxf(acc2[2*i] + B2[slot*8 + 2*i], 0.f);
    float v1 = fmaxf(acc2[2*i+1] + B2[slot*8 + 2*i+1], 0.f);
    pk[i] = (unsigned)f2bf(v0) | ((unsigned)f2bf(v1) << 16);
  }
  *(u32x4*)dst = pk;
}

// ---------------- processed_memory (bf16) + enc bf16 copy ----------------
__global__ __launch_bounds__(NTH, 1) void pm_k(float* __restrict__ ws,
    const float* __restrict__ enc, const float* __restrict__ memW){
  int wg = blockIdx.x, tid = threadIdx.x;
  int b = wg & 63, th = wg >> 6;
  int slot = tid & 7, tt = tid >> 3;
  int trow = th * 64 + tt;
  const float* er = enc + ((size_t)(b * 512 + trow)) * 256;
  f32x4 acc[8];
  #pragma unroll
  for (int i = 0; i < 8; ++i) acc[i] = 0.f;
  for (int k = 0; k < 256; ++k){
    float ev = er[k];
    const f32x4* wr = (const f32x4*)(memW + k * 256 + slot * 32);
    #pragma unroll
    for (int i = 0; i < 8; ++i) acc[i] += ev * wr[i];
  }
  unsigned short* pmB = (unsigned short*)(ws + OFF_PMB);
  unsigned short* dst = pmB + ((size_t)(b * 512 + trow)) * 256 + slot * 32;
  #pragma unroll
  for (int i = 0; i < 8; ++i){
    u32x2 pk;
    pk[0] = (unsigned)f2bf(acc[i][0]) | ((unsigned)f2bf(acc[i][1]) << 16);
    pk[1] = (unsigned)f2bf(acc[i][2]) | ((unsigned)f2bf(acc[i][3]) << 16);
    *(u32x2*)(dst + i * 4) = pk;
  }
  const float* e2 = enc + ((size_t)(b * 512 + th * 64)) * 256;
  unsigned* eb = (unsigned*)((unsigned short*)(ws + OFF_ENCB) + ((size_t)(b * 512 + th * 64)) * 256);
  for (int i = tid; i < 64 * 128; i += NTH){
    float v0 = e2[i * 2], v1 = e2[i * 2 + 1];
    eb[i] = (unsigned)f2bf(v0) | ((unsigned)f2bf(v1) << 16);
  }
}

// ---------------- persistent recurrent decoder ----------------
// 2-interval schedule (was 3): decoder GRUs are a pure downstream pipeline,
// lagged one step behind the attention recurrence.
//   X(t) = P2(t) attention scoring/ctx  ||  P5(t-1) GRU2
//   Y(t) = P0(t+1) attention-GRU        ||  P4(t) GRU1  (share ahL/cnL LDS)
// 2 group-local gbars/step. pm/enc slices in registers; biases hoisted.
__global__ __launch_bounds__(NTH, 2) void decoder_k(
    float* __restrict__ ws, float* __restrict__ out,
    const int* __restrict__ memlen,
    const float* __restrict__ vW,
    const float* __restrict__ attBi, const float* __restrict__ attBh,
    const float* __restrict__ projB,
    const float* __restrict__ d1Bh,
    const float* __restrict__ d2Bi, const float* __restrict__ d2Bh)
{
  const int wg = blockIdx.x, tid = threadIdx.x;
  int* bar = (int*)ws;
  float* attH = ws + OFF_ATTH;       // [2][64][256]
  float* h1a  = ws + OFF_H1;
  float* h2a  = ws + OFF_H2;
  float* const curB[2]  = { ws + OFF_CURP, ws + OFF_Q };
  float* const attSB[2] = { ws + OFF_ATTS, ws + OFF_ATTS + 64 };
  float* d1v  = ws + OFF_D1;
  const float* C1v = ws + OFF_C1;
  const unsigned short* preB16 = (const unsigned short*)(ws + OFF_PRE);
  const unsigned short* pmB  = (const unsigned short*)(ws + OFF_PMB);
  const unsigned short* encB = (const unsigned short*)(ws + OFF_ENCB);
  const unsigned short* qtb = (const unsigned short*)(out + GOFF);
  float* d2a  = ws + OFF_D2A;

  // LDS pool: X and Y overlays (separated by gbar), 16128 floats = 64.5KB
  __shared__ float POOL[16128];
  float* const ahL  = POOL;           // Y: [16][260] attH(t) rows
  float* const cnL  = POOL + 4160;    // Y: [16][260] ctxN(t) rows
  float* const h1L  = POOL + 8320;    // Y: [16][260] h1(t-1) rows
  float* const xpre = POOL + 12480;   // Y: [16][132] pre(t+1)
  float* const dL   = POOL;           // X: [16][260] d1(t-1) rows
  float* const h2L  = POOL + 4160;    // X: [16][260] h2(t-2) rows
  float* const ctxP = POOL + 8320;    // X: [4096] ctx partials
  float* const qIn  = POOL + 12416;   // X: [256] attH(t) row b2
  float* const ewGi  = POOL + 14592;  // [192]
  float* const ewGh  = POOL + 14784;  // [192]
  float* const ewGi2 = POOL + 14976;  // [192]
  float* const ewGh2 = POOL + 15168;  // [192]
  float* const pdec  = POOL + 15360;  // [128]
  float* const qL    = POOL + 15488;  // [256]
  float* const vL    = POOL + 15744;  // [256]
  float* const eL    = POOL + 16000;  // [128]

  if (tid < 256) vL[tid] = vW[tid];

  // group decomposition: g owns batches [g*16, g*16+16)
  const int g = wg >> 6, l = wg & 63;
  const int sl = l;
  const int b0 = g << 4;
  const int b2 = b0 + (l >> 2), ch2 = l & 3;
  const int len2 = memlen[b2];
  const unsigned short* blob = (const unsigned short*)(ws + OFF_BLOB) + (size_t)sl * BLOB_STR;

  const int bq = tid & 15, x = tid >> 4;
  const int cs = (x >= 12 && x < 24) ? (x - 12) : x;
  const int gg = cs % 3, jh = cs / 3;
  const int col = gg * 256 + sl * 4 + jh;

  const int r0 = tid >> 6, c0 = (tid & 63) << 2;
  const int r1 = r0 + 8;
  const int prr = tid >> 4, pcc = (tid & 15) * 8;

  // hoisted per-thread biases
  float rb0 = 0.f, rb1 = 0.f, rb2 = 0.f;
  if (x < 12){ rb0 = attBi[col]; rb1 = C1v[col];  rb2 = d2Bi[col]; }
  else if (x < 24){ rb0 = attBh[col]; rb1 = d1Bh[col]; rb2 = d2Bh[col]; }
  float pjB2 = 0.f;
  if (tid >= 64 && tid < 128) pjB2 = projB[sl*4 + ((tid - 64) >> 4)];

  // persistent register staging of pm/enc slices
  u32x4 pmv[8], env[8];
  {
    int te = tid >> 2, part = tid & 3;
    const u32x4* pmp = (const u32x4*)(pmB + ((size_t)(b2*512 + ch2*128 + te))*256 + part*64);
    #pragma unroll
    for (int i = 0; i < 8; ++i) pmv[i] = pmp[i];
    int ich = tid >> 5, dblk = tid & 31;
    const unsigned short* ep = encB + ((size_t)(b2*512 + ch2*128 + ich*8))*256 + dblk*8;
    #pragma unroll
    for (int i = 0; i < 8; ++i) env[i] = *(const u32x4*)(ep + i*256);
  }

  // initial loads for Y(-1): attH(-1)=attH[1] (zeroed), h1(-?) garbage-ok, pre row 0
  f32x4 eA0, eA1, eH0, eH1;
  u32x4 ppre = 0u;
  eA0 = cload16(attH + 16384 + ((b0+r0)<<8) + c0);
  eA1 = cload16(attH + 16384 + ((b0+r1)<<8) + c0);
  eH0 = cload16(h1a + ((b0+r0)<<8) + c0);
  eH1 = cload16(h1a + ((b0+r1)<<8) + c0);
  if (tid < 256) ppre = cload16u(preB16 + (b0 + prr)*128 + pcc);

  int bn = 0;
  for (int t = -1; t <= 400; ++t){
    const int w = t & 1, wn = w ^ 1;

    if (t >= 0){
      // ================= X(t): P2(t) || P5(t-1) =================
      const bool doP2 = (t < 400), doP5 = (t >= 1);
      f32x4 vD0 = cload16(d1v + ((b0+r0)<<8) + c0);
      f32x4 vD1 = cload16(d1v + ((b0+r1)<<8) + c0);
      f32x4 vH0 = cload16(h2a + w*16384 + ((b0+r0)<<8) + c0);
      f32x4 vH1 = cload16(h2a + w*16384 + ((b0+r1)<<8) + c0);
      f32x4 qv = 0.f;
      if (tid < 64) qv = cload16(attH + w*16384 + b2*256 + tid*4);
      // early-issue Y(t)-bound loads (attH(t), h1(t-1) stable since last gbar)
      eA0 = cload16(attH + w*16384 + ((b0+r0)<<8) + c0);
      eA1 = cload16(attH + w*16384 + ((b0+r1)<<8) + c0);
      eH0 = cload16(h1a + wn*16384 + ((b0+r0)<<8) + c0);
      eH1 = cload16(h1a + wn*16384 + ((b0+r1)<<8) + c0);
      {
        int tn = (t + 1 < TDEC) ? (t + 1) : (TDEC - 1);
        if (tid < 256) ppre = cload16u(preB16 + (size_t)tn*8192 + (b0 + prr)*128 + pcc);
      }
      asm volatile("s_waitcnt vmcnt(0)" : "+v"(vD0),"+v"(vD1),"+v"(vH0),"+v"(vH1),"+v"(qv));
      __builtin_amdgcn_sched_barrier(0);
      if (tid < 64) *(f32x4*)(qIn + tid*4) = qv;
      *(f32x4*)(dL + r0*260 + c0) = vD0;  *(f32x4*)(dL + r1*260 + c0) = vD1;
      *(f32x4*)(h2L + r0*260 + c0) = vH0; *(f32x4*)(h2L + r1*260 + c0) = vH1;
      ldsbar();
      // ---- dots: q-GEMV (all threads, in-wave K-split) + P5 GRU2 dots ----
      if (doP2){
        int lane = tid & 63;
        int j = (tid >> 6)*32 + (lane & 31), hf = lane >> 5;
        const unsigned short* qw = qtb + j*8 + (size_t)hf*32768;
        const float* qx = qIn + hf*128;
        f32x4 aA = 0.f, aB = 0.f;
        #pragma unroll 4
        for (int it = 0; it < 16; ++it){
          u32x4 u = *(const u32x4*)(qw + (size_t)it*2048);
          f32x4 a = *(const f32x4*)(qx + it*8);
          f32x4 b = *(const f32x4*)(qx + it*8 + 4);
          f32x4 w0, w1;
          w0[0]=blo(u[0]); w0[1]=bhi(u[0]); w0[2]=blo(u[1]); w0[3]=bhi(u[1]);
          w1[0]=blo(u[2]); w1[1]=bhi(u[2]); w1[2]=blo(u[3]); w1[3]=bhi(u[3]);
          aA += w0*a; aB += w1*b;
        }
        f32x4 s4 = aA + aB;
        float s = s4[0]+s4[1]+s4[2]+s4[3];
        s += __shfl_xor(s, 32);
        if (hf == 0) qL[j] = s;
      }
      if (doP5){
        if (x < 12)
          ewGi[cs*16 + bq] = bdot<32>(blob + BO_I2 + cs*256, dL + bq*260) + rb2;
        else if (x < 24)
          ewGh[cs*16 + bq] = bdot<32>(blob + BO_H2 + cs*256, h2L + bq*260) + rb2;
      }
      ldsbar();
      // ---- scoring (P2) + P5 combine ----
      if (doP2){
        int te = tid >> 2, part = tid & 3;
        int ge = ch2*128 + te;
        float a4 = 0.f;
        #pragma unroll
        for (int i = 0; i < 8; ++i){
          u32x4 u = pmv[i];
          int kb = part*64 + i*8;
          a4 += ftanh(blo(u[0]) + qL[kb+0]) * vL[kb+0];
          a4 += ftanh(bhi(u[0]) + qL[kb+1]) * vL[kb+1];
          a4 += ftanh(blo(u[1]) + qL[kb+2]) * vL[kb+2];
          a4 += ftanh(bhi(u[1]) + qL[kb+3]) * vL[kb+3];
          a4 += ftanh(blo(u[2]) + qL[kb+4]) * vL[kb+4];
          a4 += ftanh(bhi(u[2]) + qL[kb+5]) * vL[kb+5];
          a4 += ftanh(blo(u[3]) + qL[kb+6]) * vL[kb+6];
          a4 += ftanh(bhi(u[3]) + qL[kb+7]) * vL[kb+7];
        }
        a4 += __shfl_xor(a4, 1);
        a4 += __shfl_xor(a4, 2);
        float e = (ge < len2) ? __expf(a4) : 0.f;
        if (part == 0){
          eL[te] = e;
          out[AOFF + ((size_t)(b2*TDEC + t))*512 + ge] = e;
        }
      }
      if (doP5 && tid < 64){
        int bt = tid & 15, jj = tid >> 4;
        int j = sl*4 + jj;
        float ir = ewGi[(jj*3+0)*16+bt] + ewGh[(jj*3+0)*16+bt];
        float iz = ewGi[(jj*3+1)*16+bt] + ewGh[(jj*3+1)*16+bt];
        float inn = ewGi[(jj*3+2)*16+bt];
        float hn  = ewGh[(jj*3+2)*16+bt];
        float rg = fsig(ir), z = fsig(iz);
        float n = ftanh(inn + rg * hn);
        float hv = h2L[bt*260 + j];
        float hnew = (1.f - z)*n + z*hv;
        astore4(h2a + wn*16384 + (b0+bt)*256 + j, hnew);
        d2a[(size_t)(t-1)*16384 + j*64 + (b0+bt)] = hnew + dL[bt*260 + j];
      }
      ldsbar();
      if (doP2){
        if (tid < 64){
          float s = eL[tid] + eL[tid + 64];
          #pragma unroll
          for (int o = 32; o > 0; o >>= 1) s += __shfl_down(s, o);
          if (tid == 0) aadd(attSB[w] + b2, s);
        }
        {
          int ich = tid >> 5, dblk = tid & 31;
          f32x4 acA = 0.f, acB = 0.f;
          #pragma unroll
          for (int i = 0; i < 8; ++i){
            u32x4 u = env[i];
            float e = eL[ich*8 + i];
            acA[0] += e*blo(u[0]); acA[1] += e*bhi(u[0]);
            acA[2] += e*blo(u[1]); acA[3] += e*bhi(u[1]);
            acB[0] += e*blo(u[2]); acB[1] += e*bhi(u[2]);
            acB[2] += e*blo(u[3]); acB[3] += e*bhi(u[3]);
          }
          *(f32x4*)(ctxP + tid*8) = acA;
          *(f32x4*)(ctxP + tid*8 + 4) = acB;
        }
      }
      ldsbar();
      if (doP2 && tid < 256){
        int dblk = tid >> 3, d = tid & 7;
        float s = 0.f;
        #pragma unroll
        for (int i = 0; i < 16; ++i) s += ctxP[i*256 + dblk*8 + d];
        aadd(curB[w] + b2*256 + dblk*8 + d, s);
      }
    }

    gbar(bar, g, l, ++bn);
    if (t == 400) break;

    // ================= Y(t): P0(t+1) || P4(t) =================
    {
      const bool doP0 = (t <= 398), doP4 = (t >= 0);
      f32x4 vC0 = cload16(curB[w] + ((b0+r0)<<8) + c0);
      f32x4 vC1 = cload16(curB[w] + ((b0+r1)<<8) + c0);
      float s0 = aload4(attSB[w] + b0 + r0), s1 = aload4(attSB[w] + b0 + r1);
      asm volatile("s_waitcnt vmcnt(0)" : "+v"(vC0),"+v"(vC1));
      __builtin_amdgcn_sched_barrier(0);
      float iv0 = s0 > 0.f ? 1.f/s0 : 0.f, iv1 = s1 > 0.f ? 1.f/s1 : 0.f;
      *(f32x4*)(ahL + r0*260 + c0) = eA0; *(f32x4*)(ahL + r1*260 + c0) = eA1;
      *(f32x4*)(h1L + r0*260 + c0) = eH0; *(f32x4*)(h1L + r1*260 + c0) = eH1;
      *(f32x4*)(cnL + r0*260 + c0) = vC0*iv0; *(f32x4*)(cnL + r1*260 + c0) = vC1*iv1;
      if (tid < 256){
        float* xd = xpre + prr*132 + pcc;
        xd[0]=blo(ppre[0]); xd[1]=bhi(ppre[0]); xd[2]=blo(ppre[1]); xd[3]=bhi(ppre[1]);
        xd[4]=blo(ppre[2]); xd[5]=bhi(ppre[2]); xd[6]=blo(ppre[3]); xd[7]=bhi(ppre[3]);
      }
      // zero next-step accumulators (parity wn; last reader was 2 gbars ago)
      if (tid < 64) astore4(curB[wn] + wg*64 + tid, 0.f);
      if (sl == 0 && tid < 16) astore4(attSB[wn] + b0 + tid, 0.f);
      if (t >= 0 && sl == 0 && tid < 16)
        ws[OFF_SUMS + t*64 + b0 + tid] = aload4(attSB[w] + b0 + tid);
      ldsbar();
      // ---- dots ----
      if (x < 12){
        if (doP0)
          ewGi[cs*16 + bq] = bdot<16>(blob + BO_AI + cs*384, xpre + bq*132)
                           + bdot<32>(blob + BO_AI + cs*384 + 128, cnL + bq*260) + rb0;
        if (doP4)
          ewGi2[cs*16 + bq] = bdot<32>(blob + BO_M1 + cs*512, ahL + bq*260)
                            + bdot<32>(blob + BO_M1 + cs*512 + 256, cnL + bq*260) + rb1;
      } else if (x < 24){
        if (doP0)
          ewGh[cs*16 + bq] = bdot<32>(blob + BO_AH + cs*256, ahL + bq*260) + rb0;
        if (doP4)
          ewGh2[cs*16 + bq] = bdot<32>(blob + BO_H1 + cs*256, h1L + bq*260) + rb1;
      } else if (doP4){
        int idx = tid - 384;
        int bq2 = idx & 15, cc = (idx >> 4) & 3, half = idx >> 6;
        pdec[idx] = bdot<32>(blob + BO_PJ + cc*512 + half*256, (half ? cnL : ahL) + bq2*260);
      }
      ldsbar();
      // ---- combines (disjoint waves) ----
      if (doP0 && tid < 64){
        int bt = tid & 15, jj = tid >> 4;
        int j = sl*4 + jj;
        float ir = ewGi[(jj*3+0)*16+bt] + ewGh[(jj*3+0)*16+bt];
        float iz = ewGi[(jj*3+1)*16+bt] + ewGh[(jj*3+1)*16+bt];
        float inn = ewGi[(jj*3+2)*16+bt];
        float hn  = ewGh[(jj*3+2)*16+bt];
        float rg = fsig(ir), z = fsig(iz);
        float n = ftanh(inn + rg * hn);
        float h = ahL[bt*260 + j];
        astore4(attH + wn*16384 + (b0+bt)*256 + j, (1.f - z)*n + z*h);
      }
      if (doP4 && tid >= 64 && tid < 128){
        int t2 = tid - 64;
        int bt = t2 & 15, jj = t2 >> 4;
        int j = sl*4 + jj;
        float ir = ewGi2[(jj*3+0)*16+bt] + ewGh2[(jj*3+0)*16+bt];
        float iz = ewGi2[(jj*3+1)*16+bt] + ewGh2[(jj*3+1)*16+bt];
        float inn = ewGi2[(jj*3+2)*16+bt];
        float hn  = ewGh2[(jj*3+2)*16+bt];
        float rg = fsig(ir), z = fsig(iz);
        float n = ftanh(inn + rg * hn);
        float hv = h1L[bt*260 + j];
        float hnew = (1.f - z)*n + z*hv;
        float dec = pdec[jj*16 + bt] + pdec[64 + jj*16 + bt] + pjB2;
        astore4(h1a + w*16384 + (b0+bt)*256 + j, hnew);
        astore4(d1v + (b0+bt)*256 + j, hnew + dec);
      }
    }
    gbar(bar, g, l, ++bn);
  }
}

// ---------------- alignment rescale ----------------
__global__ __launch_bounds__(NTH, 1) void rescale_k(const float* __restrict__ ws,
                                                    float* __restrict__ out){
  int blk = blockIdx.x;
  int b = blk / TDEC, t = blk - b * TDEC;
  float s = ws[OFF_SUMS + t*64 + b];
  float inv = (s > 0.f) ? 1.f/s : 0.f;
  out[AOFF + (size_t)blk*512 + threadIdx.x] *= inv;
}

// ---------------- deferred mel/gate heads ----------------
__global__ __launch_bounds__(NTH, 1) void outproj_k(const float* __restrict__ ws,
    float* __restrict__ out, const float* __restrict__ melW, const float* __restrict__ melB,
    const float* __restrict__ gateW, const float* __restrict__ gateB){
  int t = blockIdx.x, tid = threadIdx.x;
  int cx = tid & 255, bh = tid >> 8;
  const float* src = ws + OFF_D2A + t*16384 + bh*32;
  float acc[32];
  #pragma unroll
  for (int i = 0; i < 32; ++i) acc[i] = 0.f;
  bool ismel = (cx < 160);
  bool isgate = (cx >= 160 && cx < 162);
  for (int j = 0; j < 256; ++j){
    float wv = 0.f;
    if (ismel) wv = melW[j*160 + cx];
    else if (isgate) wv = gateW[j*2 + (cx - 160)];
    const f32x4* dp = (const f32x4*)(src + j*64);
    f32x4 vv[8];
    #pragma unroll
    for (int q = 0; q < 8; ++q) vv[q] = dp[q];
    #pragma unroll
    for (int q = 0; q < 8; ++q){
      acc[q*4+0] += vv[q][0]*wv; acc[q*4+1] += vv[q][1]*wv;
      acc[q*4+2] += vv[q][2]*wv; acc[q*4+3] += vv[q][3]*wv;
    }
  }
  if (ismel){
    float bb = melB[cx];
    #pragma unroll
    for (int i = 0; i < 32; ++i){
      int b = bh*32 + i;
      out[((size_t)(b*TDEC + t))*160 + cx] = acc[i] + bb;
    }
  } else if (isgate){
    int g = cx - 160;
    float bb = gateB[g];
    #pragma unroll
    for (int i = 0; i < 32; ++i){
      int b = bh*32 + i;
      out[GOFF + ((size_t)(b*TDEC + t))*2 + g] = fsig(acc[i] + bb);
    }
  }
}

extern "C" void kernel_launch(void* const* d_in, const int* in_sizes, int n_in,
                              void* d_out, int out_size, void* d_ws, size_t ws_size,
                              hipStream_t stream)
{
  (void)in_sizes; (void)n_in; (void)out_size; (void)ws_size;
  const float* enc   = (const float*)d_in[0];
  const float* inp   = (const float*)d_in[1];
  const int*   mlen  = (const int*)d_in[2];
  const float* preW1 = (const float*)d_in[3];
  const float* preB1 = (const float*)d_in[4];
  const float* preW2 = (const float*)d_in[5];
  const float* preB2 = (const float*)d_in[6];
  const float* memW  = (const float*)d_in[7];
  const float* qW    = (const float*)d_in[8];
  const float* vW    = (const float*)d_in[9];
  const float* attWi = (const float*)d_in[10];
  const float* attWh = (const float*)d_in[11];
  const float* attBi = (const float*)d_in[12];
  const float* attBh = (const float*)d_in[13];
  const float* projW = (const float*)d_in[14];
  const float* projB = (const float*)d_in[15];
  const float* d1Wi  = (const float*)d_in[16];
  const float* d1Wh  = (const float*)d_in[17];
  const float* d1Bi  = (const float*)d_in[18];
  const float* d1Bh  = (const float*)d_in[19];
  const float* d2Wi  = (const float*)d_in[20];
  const float* d2Wh  = (const float*)d_in[21];
  const float* d2Bi  = (const float*)d_in[22];
  const float* d2Bh  = (const float*)d_in[23];
  const float* melW  = (const float*)d_in[24];
  const float* melB  = (const float*)d_in[25];
  const float* gateW = (const float*)d_in[26];
  const float* gateB = (const float*)d_in[27];
  float* ws = (float*)d_ws;
  float* out = (float*)d_out;

  hipMemsetAsync(d_ws, 0, (size_t)ZERO_FLOATS * sizeof(float), stream);

  dim3 tt(256);
  transpose_k<<<dim3(24, 12), tt, 0, stream>>>(attWi, ws + T_WIT_A, 384, 768);
  transpose_k<<<dim3(24, 8),  tt, 0, stream>>>(attWh, ws + T_WHT_A, 256, 768);
  transpose_k<<<dim3(24, 8),  tt, 0, stream>>>(d1Wh,  ws + T_WHT1, 256, 768);
  transpose_k<<<dim3(24, 8),  tt, 0, stream>>>(d2Wi,  ws + T_WIT2, 256, 768);
  transpose_k<<<dim3(24, 8),  tt, 0, stream>>>(d2Wh,  ws + T_WHT2, 256, 768);
  transpose_k<<<dim3(8, 16),  tt, 0, stream>>>(projW, ws + T_PJT, 512, 256);
  transpose_k<<<dim3(8, 8),   tt, 0, stream>>>(qW,    ws + T_QWT, 256, 256);
  fuse_k<<<3072, 128, 0, stream>>>(projW, d1Wi, ws + T_M1);
  c1_k<<<3, 256, 0, stream>>>(projB, d1Wi, d1Bi, ws + OFF_C1);
  transpose_k<<<dim3(24, 16), tt, 0, stream>>>(ws + T_M1, ws + T_M1T, 512, 768);
  pack_k<<<64, NTH, 0, stream>>>(ws);
  qt_k<<<256, 256, 0, stream>>>(ws, out);

  prenet_k<<<dim3(TDEC, 2), NTH, 0, stream>>>(ws, inp, preW1, preB1, preW2, preB2);
  pm_k<<<512, NTH, 0, stream>>>(ws, enc, memW);
  decoder_k<<<NWG, NTH, 0, stream>>>(ws, out, mlen, vW, attBi, attBh, projB,
                                     d1Bh, d2Bi, d2Bh);
  rescale_k<<<64 * TDEC, NTH, 0, stream>>>(ws, out);
  outproj_k<<<TDEC, NTH, 0, stream>>>(ws, out, melW, melB, gateW, gateB);
}